// Round 7
// baseline (367.165 us; speedup 1.0000x reference)
//
#include <hip/hip_runtime.h>

// ---------------------------------------------------------------------------
// Fused multi-head self-attention, MI355X bf16-MFMA implementation.
// B=4, S=2048, E=1024, H=16, D=64.
// Pipeline: cvt x->bf16 | pack W^T bf16 | GEMM1 (QKV proj, bias) |
//           repack V->V^T | flash-attn (swapped-QK^T, in-reg softmax,
//           2-deep QK||softmax pipeline) | GEMM2 (out proj, bias, f32 out)
// ---------------------------------------------------------------------------

typedef __attribute__((ext_vector_type(4)))  float   f32x4;
typedef __attribute__((ext_vector_type(16))) float   f32x16;
typedef __attribute__((ext_vector_type(8)))  __bf16  bf16x8;
typedef __attribute__((ext_vector_type(4)))  __bf16  bf16x4;
typedef __attribute__((ext_vector_type(4)))  unsigned int u32x4;
typedef unsigned int u32;

__device__ __forceinline__ f32x4 fzero4() {
    f32x4 z = {0.f, 0.f, 0.f, 0.f};
    return z;
}
__device__ __forceinline__ f32x16 fzero16() {
    f32x16 z;
#pragma unroll
    for (int i = 0; i < 16; i++) z[i] = 0.f;
    return z;
}

__device__ __forceinline__ u32 cvtpk_bf16(float lo, float hi_) {
    u32 r;
    asm("v_cvt_pk_bf16_f32 %0, %1, %2" : "=v"(r) : "v"(lo), "v"(hi_));
    return r;
}

__device__ __forceinline__ void gload_lds16(const void* g, void* l) {
    __builtin_amdgcn_global_load_lds(
        (const __attribute__((address_space(1))) u32*)g,
        (__attribute__((address_space(3))) u32*)l, 16, 0, 0);
}

// ---------------------------------------------------------------------------
// fp32 -> bf16 elementwise convert (4 elems/thread, vectorized)
// ---------------------------------------------------------------------------
__global__ __launch_bounds__(256) void cvt_f32_bf16_4(
    const float* __restrict__ s, __bf16* __restrict__ d, long n) {
    long i = ((long)blockIdx.x * 256 + threadIdx.x) * 4;
    if (i >= n) return;
    float4 v = *(const float4*)(s + i);
    bf16x4 o = { (__bf16)v.x, (__bf16)v.y, (__bf16)v.z, (__bf16)v.w };
    *(bf16x4*)(d + i) = o;
}

// ---------------------------------------------------------------------------
// Batched transpose-pack: src f32 [z][R][C] -> dst bf16 [z][C][R]
// ---------------------------------------------------------------------------
__global__ __launch_bounds__(256) void pack_w_t(
    const float* __restrict__ src, __bf16* __restrict__ dst, int R, int C) {
    __shared__ float t[32][33];
    const int z = blockIdx.z;
    src += (size_t)z * R * C;
    dst += (size_t)z * R * C;
    const int r0 = blockIdx.x * 32, c0 = blockIdx.y * 32;
    const int x = threadIdx.x, y = threadIdx.y;
#pragma unroll
    for (int i = 0; i < 4; i++)
        t[y + i * 8][x] = src[(size_t)(r0 + y + i * 8) * C + c0 + x];
    __syncthreads();
#pragma unroll
    for (int i = 0; i < 4; i++)
        dst[(size_t)(c0 + y + i * 8) * R + r0 + x] = (__bf16)t[x][y + i * 8];
}

// ---------------------------------------------------------------------------
// bias pack: bqkv[t*1024 + r] = {bq,bk,bv}[r]
// ---------------------------------------------------------------------------
__global__ __launch_bounds__(256) void pack_bias(
    const float* __restrict__ bq, const float* __restrict__ bk,
    const float* __restrict__ bv, float* __restrict__ bqkv) {
    int n = blockIdx.x * 256 + threadIdx.x;
    if (n >= 3072) return;
    int t = n >> 10, r = n & 1023;
    const float* s = (t == 0) ? bq : (t == 1) ? bk : bv;
    bqkv[n] = s[r];
}

// ---------------------------------------------------------------------------
// GEMM, m97 structure: C[M][N](+bias) = A[M][K] * Bt[N][K]^T
// 128x128 tile, BK=32, 256 threads (4 waves 2x2), global_load_lds staging.
// ---------------------------------------------------------------------------
template <bool F32OUT>
__global__ __launch_bounds__(256) void gemm_bt(
    const __bf16* __restrict__ A, const __bf16* __restrict__ Bt,
    const float* __restrict__ bias, void* __restrict__ Cout,
    int M, int N, int K, int ldc) {
    __shared__ __bf16 As[128 * 32];
    __shared__ __bf16 Bs[128 * 32];
    const int tid  = threadIdx.x;
    const int lane = tid & 63, wid = tid >> 6;
    const int wr = wid >> 1, wc = wid & 1;
    const int l15 = lane & 15, l4 = lane >> 4;
    const int bn = blockIdx.x, bm = blockIdx.y;
    const long arow = (long)bm * 128 + (tid >> 2);
    const long brow = (long)bn * 128 + (tid >> 2);
    const int  kcol = (tid & 3) * 8;

    f32x4 acc[4][4];
#pragma unroll
    for (int i = 0; i < 4; i++)
#pragma unroll
        for (int j = 0; j < 4; j++) acc[i][j] = fzero4();

    for (int k0 = 0; k0 < K; k0 += 32) {
        gload_lds16(A + arow * K + k0 + kcol,        (char*)As + wid * 1024);
        gload_lds16(A + (arow + 64) * K + k0 + kcol, (char*)As + 4096 + wid * 1024);
        gload_lds16(Bt + brow * K + k0 + kcol,        (char*)Bs + wid * 1024);
        gload_lds16(Bt + (brow + 64) * K + k0 + kcol, (char*)Bs + 4096 + wid * 1024);
        __syncthreads();
        bf16x8 a[4], b[4];
#pragma unroll
        for (int mi = 0; mi < 4; mi++)
            a[mi] = *(const bf16x8*)&As[(wr * 64 + mi * 16 + l15) * 32 + l4 * 8];
#pragma unroll
        for (int ni = 0; ni < 4; ni++)
            b[ni] = *(const bf16x8*)&Bs[(wc * 64 + ni * 16 + l15) * 32 + l4 * 8];
#pragma unroll
        for (int mi = 0; mi < 4; mi++)
#pragma unroll
            for (int ni = 0; ni < 4; ni++)
                acc[mi][ni] = __builtin_amdgcn_mfma_f32_16x16x32_bf16(
                    a[mi], b[ni], acc[mi][ni], 0, 0, 0);
        __syncthreads();
    }

#pragma unroll
    for (int mi = 0; mi < 4; mi++)
#pragma unroll
        for (int ni = 0; ni < 4; ni++) {
            const int row = bm * 128 + wr * 64 + mi * 16 + l4 * 4;
            const int col = bn * 128 + wc * 64 + ni * 16 + l15;
            const float bv = bias ? bias[col] : 0.f;
#pragma unroll
            for (int r = 0; r < 4; r++) {
                float v = acc[mi][ni][r] + bv;
                if (F32OUT)
                    ((float*)Cout)[(long)(row + r) * ldc + col] = v;
                else
                    ((__bf16*)Cout)[(long)(row + r) * ldc + col] = (__bf16)v;
            }
        }
}

// ---------------------------------------------------------------------------
// V repack: QKV[(b*S+s)*3072 + 2048 + h*64 + d] -> VT[(bh*64 + d)*2048 + s]
// ---------------------------------------------------------------------------
__global__ __launch_bounds__(256) void repack_vt(
    const __bf16* __restrict__ QKV, __bf16* __restrict__ VT) {
    __shared__ __bf16 t[32][33];
    const int s0 = blockIdx.x * 32, d0 = blockIdx.y * 32, bh = blockIdx.z;
    const int b = bh >> 4, h = bh & 15;
    const int x = threadIdx.x, y = threadIdx.y;
    const __bf16* src = QKV + (size_t)(b * 2048) * 3072 + 2048 + h * 64;
#pragma unroll
    for (int i = 0; i < 4; i++)
        t[y + i * 8][x] = src[(size_t)(s0 + y + i * 8) * 3072 + d0 + x];
    __syncthreads();
    __bf16* dst = VT + (size_t)bh * 64 * 2048;
#pragma unroll
    for (int i = 0; i < 4; i++)
        dst[(size_t)(d0 + y + i * 8) * 2048 + s0 + x] = t[x][y + i * 8];
}

// ---------------------------------------------------------------------------
// Flash attention fwd, v7 = v6 + 2-deep score pipeline (T15 analog):
// steady-state step t runs QK^T(t+1) on the MFMA pipe concurrently with
// softmax(t) on the VALU pipe, then PV(t). Two statically-named score sets
// (sA,sB) alternate via pair-unrolled loop (no runtime indexing -> no
// scratch). Per-tile math is bit-identical to v6.
// Block = (b, h, 128-row Q tile); 4 waves x 32 q-rows. KV tile = 64.
//   S^T = mfma(A=K, B=Q):   lane q-col = lane&31 -> ONE q row per lane.
//   O^T = mfma(A=V^T, B=P^T): same lane->q mapping, scalar m/l/alpha.
// ---------------------------------------------------------------------------

#define KLOAD(KN, T0)                                                          \
  _Pragma("unroll")                                                            \
  for (int f = 0; f < 8; f++) {                                                \
    const int tc = f >> 2, kk = f & 3;                                         \
    KN[f] = *(const bf16x8*)(Kb + (size_t)((T0) + tc * 32 + l31) * LDQ +       \
                             kk * 16 + hi * 8);                                \
  }

#define VLOAD(VF, T0)                                                          \
  _Pragma("unroll")                                                            \
  for (int f = 0; f < 8; f++) {                                                \
    const int dc = f >> 2, kkt = f & 3;                                        \
    VF[f] = *(const bf16x8*)(Vb + (size_t)(dc * 32 + l31) * S + (T0) +         \
                             kkt * 16 + hi * 8);                               \
  }

#define QK8(S0, S1, KC)                                                        \
  {                                                                            \
    S0 = fzero16();                                                            \
    S1 = fzero16();                                                            \
    __builtin_amdgcn_s_setprio(1);                                             \
    _Pragma("unroll")                                                          \
    for (int kk = 0; kk < 4; kk++) {                                           \
      S0 = __builtin_amdgcn_mfma_f32_32x32x16_bf16(KC[kk],     qf[kk], S0, 0, 0, 0); \
      S1 = __builtin_amdgcn_mfma_f32_32x32x16_bf16(KC[4 + kk], qf[kk], S1, 0, 0, 0); \
    }                                                                          \
    __builtin_amdgcn_s_setprio(0);                                             \
  }

#define SMPV(S0, S1, VF)                                                       \
  {                                                                            \
    /* ---- row max: log-depth tree + cross-half shfl ---- */                  \
    float mm[16];                                                              \
    _Pragma("unroll")                                                          \
    for (int i = 0; i < 16; i++) mm[i] = fmaxf(S0[i], S1[i]);                  \
    _Pragma("unroll")                                                          \
    for (int st = 8; st >= 1; st >>= 1)                                        \
      _Pragma("unroll")                                                        \
      for (int i = 0; i < st; i++) mm[i] = fmaxf(mm[i], mm[i + st]);           \
    const float pm = fmaxf(mm[0], __shfl_xor(mm[0], 32));                      \
    /* ---- unconditional rescale (P stays in [0,1]) ---- */                   \
    const float mnew = fmaxf(m_r, pm);                                         \
    const float alpha = exp2f((m_r - mnew) * csc);                             \
    m_r = mnew;                                                                \
    l_r *= alpha;                                                              \
    _Pragma("unroll")                                                          \
    for (int i = 0; i < 16; i++) { o0[i] *= alpha; o1[i] *= alpha; }           \
    const float mc = m_r * csc;                                                \
    float ss[16];                                                              \
    _Pragma("unroll")                                                          \
    for (int i = 0; i < 16; i++) {                                             \
      float p0 = exp2f(S0[i] * csc - mc); S0[i] = p0;                          \
      float p1 = exp2f(S1[i] * csc - mc); S1[i] = p1;                          \
      ss[i] = p0 + p1;                                                         \
    }                                                                          \
    /* ---- P -> bf16 B-frags in-register, PV MFMA ---- */                     \
    _Pragma("unroll")                                                          \
    for (int kkt = 0; kkt < 4; kkt++) {                                        \
      const int r0 = (kkt & 1) * 8;                                            \
      u32 w0, w1, w2, w3;                                                      \
      if (kkt < 2) {                                                           \
        w0 = cvtpk_bf16(S0[r0],     S0[r0 + 1]);                               \
        w1 = cvtpk_bf16(S0[r0 + 2], S0[r0 + 3]);                               \
        w2 = cvtpk_bf16(S0[r0 + 4], S0[r0 + 5]);                               \
        w3 = cvtpk_bf16(S0[r0 + 6], S0[r0 + 7]);                               \
      } else {                                                                 \
        w0 = cvtpk_bf16(S1[r0],     S1[r0 + 1]);                               \
        w1 = cvtpk_bf16(S1[r0 + 2], S1[r0 + 3]);                               \
        w2 = cvtpk_bf16(S1[r0 + 4], S1[r0 + 5]);                               \
        w3 = cvtpk_bf16(S1[r0 + 6], S1[r0 + 7]);                               \
      }                                                                        \
      asm("v_permlane32_swap_b32 %0, %1" : "+v"(w0), "+v"(w2));                \
      asm("v_permlane32_swap_b32 %0, %1" : "+v"(w1), "+v"(w3));                \
      u32x4 pw = {w0, w1, w2, w3};                                             \
      bf16x8 pf = __builtin_bit_cast(bf16x8, pw);                              \
      __builtin_amdgcn_s_setprio(1);                                           \
      o0 = __builtin_amdgcn_mfma_f32_32x32x16_bf16(VF[kkt],     pf, o0, 0, 0, 0); \
      o1 = __builtin_amdgcn_mfma_f32_32x32x16_bf16(VF[4 + kkt], pf, o1, 0, 0, 0); \
      __builtin_amdgcn_s_setprio(0);                                           \
    }                                                                          \
    /* ---- row sum (off PV critical path) ---- */                             \
    _Pragma("unroll")                                                          \
    for (int st = 8; st >= 1; st >>= 1)                                        \
      _Pragma("unroll")                                                        \
      for (int i = 0; i < st; i++) ss[i] += ss[i + st];                        \
    l_r += ss[0] + __shfl_xor(ss[0], 32);                                      \
  }

// One pipeline step for tile T0: V(T0) loads; QK(T0+64) into the NEXT score
// set; prefetch K(T0+128) into the buffer whose tile was consumed last step;
// softmax+PV of tile T0 from the CURRENT score set.
#define STEP(SC0, SC1, SN0, SN1, KNEXT, KPREF, T0, DOQK, DOPREF)               \
  {                                                                            \
    bf16x8 vf[8];                                                              \
    VLOAD(vf, T0)                                                              \
    if (DOQK) QK8(SN0, SN1, KNEXT)                                             \
    if (DOPREF) KLOAD(KPREF, (T0) + 128)                                       \
    SMPV(SC0, SC1, vf)                                                         \
  }

__global__ __launch_bounds__(256, 2) void attn_fwd(
    const __bf16* __restrict__ QKV, const __bf16* __restrict__ VT,
    __bf16* __restrict__ Z) {
    const int S = 2048, LDQ = 3072;
    const int blk = blockIdx.x;
    const int qt = blk & 15, bh = blk >> 4, b = bh >> 4, h = bh & 15;
    const int tid = threadIdx.x, wid = tid >> 6, lane = tid & 63;
    const int l31 = lane & 31, hi = lane >> 5;

    __shared__ __bf16 Tl[128][72];   // epilogue transpose only (pad 72)

    const __bf16* Qb = QKV + (size_t)b * S * LDQ + h * 64;
    const __bf16* Kb = Qb + 1024;
    const __bf16* Vb = VT + (size_t)bh * 64 * S;
    const int qrow = qt * 128 + wid * 32;

    bf16x8 qf[4];
#pragma unroll
    for (int kk = 0; kk < 4; kk++)
        qf[kk] = *(const bf16x8*)(Qb + (size_t)(qrow + l31) * LDQ + kk * 16 + hi * 8);

    f32x16 o0 = fzero16(), o1 = fzero16();
    f32x16 sA0, sA1, sB0, sB1;
    float m_r = -1e30f, l_r = 0.f;
    const float csc = 0.18033688011f;   // log2(e) / sqrt(64)

    bf16x8 kA[8], kB[8];
    KLOAD(kA, 0)
    KLOAD(kB, 64)
    QK8(sA0, sA1, kA)

    for (int t0 = 0; t0 < S; t0 += 128) {
        STEP(sA0, sA1, sB0, sB1, kB, kA, t0,      true,             t0 + 128 < S)
        STEP(sB0, sB1, sA0, sA1, kA, kB, t0 + 64, t0 + 128 < S,     t0 + 192 < S)
    }

    // ---- epilogue: normalize, transpose via LDS, coalesced store ----
    const float inv = 1.0f / l_r;
    const int trow = wid * 32 + l31;
#pragma unroll
    for (int g = 0; g < 4; g++) {
        bf16x4 t4a, t4b;
#pragma unroll
        for (int j = 0; j < 4; j++) {
            t4a[j] = (__bf16)(o0[4 * g + j] * inv);
            t4b[j] = (__bf16)(o1[4 * g + j] * inv);
        }
        *(bf16x4*)&Tl[trow][g * 8 + hi * 4]      = t4a;   // d = 8g+4hi+j
        *(bf16x4*)&Tl[trow][32 + g * 8 + hi * 4] = t4b;   // d = 32+8g+4hi+j
    }
    asm volatile("s_waitcnt lgkmcnt(0)" ::: "memory");
    __builtin_amdgcn_sched_barrier(0);

    const int rr = wid * 32 + (lane >> 1);
    const int ch = (lane & 1) * 32;
#pragma unroll
    for (int i = 0; i < 4; i++) {
        bf16x8 z = *(const bf16x8*)&Tl[rr][ch + i * 8];
        *(bf16x8*)&Z[((size_t)b * S + qt * 128 + rr) * 1024 + h * 64 + ch + i * 8] = z;
    }
}

// ---------------------------------------------------------------------------
// Launcher
// ---------------------------------------------------------------------------
extern "C" void kernel_launch(void* const* d_in, const int* in_sizes, int n_in,
                              void* d_out, int out_size, void* d_ws, size_t ws_size,
                              hipStream_t stream) {
    const float* x  = (const float*)d_in[0];
    const float* Wq = (const float*)d_in[1];
    const float* Wk = (const float*)d_in[2];
    const float* Wv = (const float*)d_in[3];
    const float* bq = (const float*)d_in[4];
    const float* bk = (const float*)d_in[5];
    const float* bv = (const float*)d_in[6];
    const float* Wo = (const float*)d_in[7];
    const float* bo = (const float*)d_in[8];
    float* out = (float*)d_out;

    // workspace carve-up (~109 MB)
    char* p = (char*)d_ws;
    __bf16* xb   = (__bf16*)p; p += 8192L * 1024 * 2;
    __bf16* Wqkv = (__bf16*)p; p += 3072L * 1024 * 2;
    float*  bqkv = (float*)p;  p += 3072L * 4;
    __bf16* QKV  = (__bf16*)p; p += 8192L * 3072 * 2;
    __bf16* VTb  = (__bf16*)p; p += 64L * 64 * 2048 * 2;
    __bf16* Zb   = (__bf16*)p; p += 8192L * 1024 * 2;
    __bf16* Wot  = (__bf16*)p; p += 1024L * 1024 * 2;

    cvt_f32_bf16_4<<<8192, 256, 0, stream>>>(x, xb, 8192L * 1024);
    pack_w_t<<<dim3(32, 2, 16), dim3(32, 8), 0, stream>>>(Wq, Wqkv,                1024, 64);
    pack_w_t<<<dim3(32, 2, 16), dim3(32, 8), 0, stream>>>(Wk, Wqkv + 1024L * 1024, 1024, 64);
    pack_w_t<<<dim3(32, 2, 16), dim3(32, 8), 0, stream>>>(Wv, Wqkv + 2048L * 1024, 1024, 64);
    pack_w_t<<<dim3(32, 32, 1), dim3(32, 8), 0, stream>>>(Wo, Wot, 1024, 1024);
    pack_bias<<<12, 256, 0, stream>>>(bq, bk, bv, bqkv);

    // QKV projection: [8192,1024] x [1024,3072] + bias -> bf16 [8192,3072]
    gemm_bt<false><<<dim3(24, 64), 256, 0, stream>>>(xb, Wqkv, bqkv, QKV,
                                                     8192, 3072, 1024, 3072);
    repack_vt<<<dim3(64, 2, 64), dim3(32, 8), 0, stream>>>(QKV, VTb);
    attn_fwd<<<1024, 256, 0, stream>>>(QKV, VTb, Zb);
    // out projection: [8192,1024] x [1024,1024] + bo -> f32 out
    gemm_bt<true><<<dim3(8, 64), 256, 0, stream>>>(Zb, Wot, bo, out,
                                                   8192, 1024, 1024, 1024);
}

// Round 8
// 363.105 us; speedup vs baseline: 1.0112x; 1.0112x over previous
//
#include <hip/hip_runtime.h>

// ---------------------------------------------------------------------------
// Fused multi-head self-attention, MI355X bf16-MFMA implementation.
// B=4, S=2048, E=1024, H=16, D=64.
// Pipeline: cvt x->bf16 | pack W^T bf16 | GEMM1 (QKV proj, bias) |
//           repack V->V^T | flash-attn (swapped-QK^T, in-reg softmax) |
//           GEMM2 (out proj, bias, f32 out)
// ---------------------------------------------------------------------------

typedef __attribute__((ext_vector_type(4)))  float   f32x4;
typedef __attribute__((ext_vector_type(16))) float   f32x16;
typedef __attribute__((ext_vector_type(8)))  __bf16  bf16x8;
typedef __attribute__((ext_vector_type(4)))  __bf16  bf16x4;
typedef __attribute__((ext_vector_type(4)))  unsigned int u32x4;
typedef unsigned int u32;

__device__ __forceinline__ f32x4 fzero4() {
    f32x4 z = {0.f, 0.f, 0.f, 0.f};
    return z;
}
__device__ __forceinline__ f32x16 fzero16() {
    f32x16 z;
#pragma unroll
    for (int i = 0; i < 16; i++) z[i] = 0.f;
    return z;
}

__device__ __forceinline__ u32 cvtpk_bf16(float lo, float hi_) {
    u32 r;
    asm("v_cvt_pk_bf16_f32 %0, %1, %2" : "=v"(r) : "v"(lo), "v"(hi_));
    return r;
}

__device__ __forceinline__ void gload_lds16(const void* g, void* l) {
    __builtin_amdgcn_global_load_lds(
        (const __attribute__((address_space(1))) u32*)g,
        (__attribute__((address_space(3))) u32*)l, 16, 0, 0);
}

// ---------------------------------------------------------------------------
// fp32 -> bf16 elementwise convert (4 elems/thread, vectorized)
// ---------------------------------------------------------------------------
__global__ __launch_bounds__(256) void cvt_f32_bf16_4(
    const float* __restrict__ s, __bf16* __restrict__ d, long n) {
    long i = ((long)blockIdx.x * 256 + threadIdx.x) * 4;
    if (i >= n) return;
    float4 v = *(const float4*)(s + i);
    bf16x4 o = { (__bf16)v.x, (__bf16)v.y, (__bf16)v.z, (__bf16)v.w };
    *(bf16x4*)(d + i) = o;
}

// ---------------------------------------------------------------------------
// Batched transpose-pack: src f32 [z][R][C] -> dst bf16 [z][C][R]
// ---------------------------------------------------------------------------
__global__ __launch_bounds__(256) void pack_w_t(
    const float* __restrict__ src, __bf16* __restrict__ dst, int R, int C) {
    __shared__ float t[32][33];
    const int z = blockIdx.z;
    src += (size_t)z * R * C;
    dst += (size_t)z * R * C;
    const int r0 = blockIdx.x * 32, c0 = blockIdx.y * 32;
    const int x = threadIdx.x, y = threadIdx.y;
#pragma unroll
    for (int i = 0; i < 4; i++)
        t[y + i * 8][x] = src[(size_t)(r0 + y + i * 8) * C + c0 + x];
    __syncthreads();
#pragma unroll
    for (int i = 0; i < 4; i++)
        dst[(size_t)(c0 + y + i * 8) * R + r0 + x] = (__bf16)t[x][y + i * 8];
}

// ---------------------------------------------------------------------------
// bias pack: bqkv[t*1024 + r] = {bq,bk,bv}[r]
// ---------------------------------------------------------------------------
__global__ __launch_bounds__(256) void pack_bias(
    const float* __restrict__ bq, const float* __restrict__ bk,
    const float* __restrict__ bv, float* __restrict__ bqkv) {
    int n = blockIdx.x * 256 + threadIdx.x;
    if (n >= 3072) return;
    int t = n >> 10, r = n & 1023;
    const float* s = (t == 0) ? bq : (t == 1) ? bk : bv;
    bqkv[n] = s[r];
}

// ---------------------------------------------------------------------------
// GEMM, m97 structure: C[M][N](+bias) = A[M][K] * Bt[N][K]^T
// 128x128 tile, BK=32, 256 threads (4 waves 2x2), global_load_lds staging.
// ---------------------------------------------------------------------------
template <bool F32OUT>
__global__ __launch_bounds__(256) void gemm_bt(
    const __bf16* __restrict__ A, const __bf16* __restrict__ Bt,
    const float* __restrict__ bias, void* __restrict__ Cout,
    int M, int N, int K, int ldc) {
    __shared__ __bf16 As[128 * 32];
    __shared__ __bf16 Bs[128 * 32];
    const int tid  = threadIdx.x;
    const int lane = tid & 63, wid = tid >> 6;
    const int wr = wid >> 1, wc = wid & 1;
    const int l15 = lane & 15, l4 = lane >> 4;
    const int bn = blockIdx.x, bm = blockIdx.y;
    const long arow = (long)bm * 128 + (tid >> 2);
    const long brow = (long)bn * 128 + (tid >> 2);
    const int  kcol = (tid & 3) * 8;

    f32x4 acc[4][4];
#pragma unroll
    for (int i = 0; i < 4; i++)
#pragma unroll
        for (int j = 0; j < 4; j++) acc[i][j] = fzero4();

    for (int k0 = 0; k0 < K; k0 += 32) {
        gload_lds16(A + arow * K + k0 + kcol,        (char*)As + wid * 1024);
        gload_lds16(A + (arow + 64) * K + k0 + kcol, (char*)As + 4096 + wid * 1024);
        gload_lds16(Bt + brow * K + k0 + kcol,        (char*)Bs + wid * 1024);
        gload_lds16(Bt + (brow + 64) * K + k0 + kcol, (char*)Bs + 4096 + wid * 1024);
        __syncthreads();
        bf16x8 a[4], b[4];
#pragma unroll
        for (int mi = 0; mi < 4; mi++)
            a[mi] = *(const bf16x8*)&As[(wr * 64 + mi * 16 + l15) * 32 + l4 * 8];
#pragma unroll
        for (int ni = 0; ni < 4; ni++)
            b[ni] = *(const bf16x8*)&Bs[(wc * 64 + ni * 16 + l15) * 32 + l4 * 8];
#pragma unroll
        for (int mi = 0; mi < 4; mi++)
#pragma unroll
            for (int ni = 0; ni < 4; ni++)
                acc[mi][ni] = __builtin_amdgcn_mfma_f32_16x16x32_bf16(
                    a[mi], b[ni], acc[mi][ni], 0, 0, 0);
        __syncthreads();
    }

#pragma unroll
    for (int mi = 0; mi < 4; mi++)
#pragma unroll
        for (int ni = 0; ni < 4; ni++) {
            const int row = bm * 128 + wr * 64 + mi * 16 + l4 * 4;
            const int col = bn * 128 + wc * 64 + ni * 16 + l15;
            const float bv = bias ? bias[col] : 0.f;
#pragma unroll
            for (int r = 0; r < 4; r++) {
                float v = acc[mi][ni][r] + bv;
                if (F32OUT)
                    ((float*)Cout)[(long)(row + r) * ldc + col] = v;
                else
                    ((__bf16*)Cout)[(long)(row + r) * ldc + col] = (__bf16)v;
            }
        }
}

// ---------------------------------------------------------------------------
// V repack: QKV[(b*S+s)*3072 + 2048 + h*64 + d] -> VT[(bh*64 + d)*2048 + s]
// ---------------------------------------------------------------------------
__global__ __launch_bounds__(256) void repack_vt(
    const __bf16* __restrict__ QKV, __bf16* __restrict__ VT) {
    __shared__ __bf16 t[32][33];
    const int s0 = blockIdx.x * 32, d0 = blockIdx.y * 32, bh = blockIdx.z;
    const int b = bh >> 4, h = bh & 15;
    const int x = threadIdx.x, y = threadIdx.y;
    const __bf16* src = QKV + (size_t)(b * 2048) * 3072 + 2048 + h * 64;
#pragma unroll
    for (int i = 0; i < 4; i++)
        t[y + i * 8][x] = src[(size_t)(s0 + y + i * 8) * 3072 + d0 + x];
    __syncthreads();
    __bf16* dst = VT + (size_t)bh * 64 * 2048;
#pragma unroll
    for (int i = 0; i < 4; i++)
        dst[(size_t)(d0 + y + i * 8) * 2048 + s0 + x] = t[x][y + i * 8];
}

// ---------------------------------------------------------------------------
// Flash attention fwd, v8 = v6 (launch_bounds(256,2), single score set,
// tree reductions, shfl_xor(32) cross-half, setprio) + XCD-chunk swizzle
// as the ONLY change vs round 6. Round 5's swizzle test was confounded by
// the (256,4) spill; this isolates it. Grid 1024 % 8 == 0 -> bijective.
// XCD x owns logical blocks [x*128,(x+1)*128) = 8 heads x 16 q-tiles;
// K/V per XCD = 8 x 512KB = 4MB = L2 capacity.
// Block = (b, h, 128-row Q tile); 4 waves x 32 q-rows. KV tile = 64.
//   S^T = mfma(A=K, B=Q):   lane q-col = lane&31 -> ONE q row per lane.
//   O^T = mfma(A=V^T, B=P^T): same lane->q mapping, scalar m/l/alpha.
// ---------------------------------------------------------------------------

#define ATTN_TILE(T0, KC, KN, PREF)                                            \
  {                                                                            \
    bf16x8 vf[8];                                                              \
    _Pragma("unroll")                                                          \
    for (int f = 0; f < 8; f++) {                                              \
      const int dc = f >> 2, kkt = f & 3;                                      \
      vf[f] = *(const bf16x8*)(Vb + (size_t)(dc * 32 + l31) * S + (T0) +       \
                               kkt * 16 + hi * 8);                             \
    }                                                                          \
    f32x16 s0 = fzero16(), s1 = fzero16();                                     \
    __builtin_amdgcn_s_setprio(1);                                             \
    _Pragma("unroll")                                                          \
    for (int kk = 0; kk < 4; kk++) {                                           \
      s0 = __builtin_amdgcn_mfma_f32_32x32x16_bf16(KC[kk],     qf[kk], s0, 0, 0, 0); \
      s1 = __builtin_amdgcn_mfma_f32_32x32x16_bf16(KC[4 + kk], qf[kk], s1, 0, 0, 0); \
    }                                                                          \
    __builtin_amdgcn_s_setprio(0);                                             \
    if (PREF) {                                                                \
      _Pragma("unroll")                                                        \
      for (int f = 0; f < 8; f++) {                                            \
        const int tc = f >> 2, kk = f & 3;                                     \
        KN[f] = *(const bf16x8*)(Kb + (size_t)((T0) + 64 + tc * 32 + l31) *    \
                                 LDQ + kk * 16 + hi * 8);                      \
      }                                                                        \
    }                                                                          \
    /* ---- row max: log-depth tree + cross-half shfl ---- */                  \
    float mm[16];                                                              \
    _Pragma("unroll")                                                          \
    for (int i = 0; i < 16; i++) mm[i] = fmaxf(s0[i], s1[i]);                  \
    _Pragma("unroll")                                                          \
    for (int st = 8; st >= 1; st >>= 1)                                        \
      _Pragma("unroll")                                                        \
      for (int i = 0; i < st; i++) mm[i] = fmaxf(mm[i], mm[i + st]);           \
    const float pm = fmaxf(mm[0], __shfl_xor(mm[0], 32));                      \
    /* ---- unconditional rescale (P stays in [0,1]) ---- */                   \
    const float mnew = fmaxf(m_r, pm);                                         \
    const float alpha = exp2f((m_r - mnew) * csc);                             \
    m_r = mnew;                                                                \
    l_r *= alpha;                                                              \
    _Pragma("unroll")                                                          \
    for (int i = 0; i < 16; i++) { o0[i] *= alpha; o1[i] *= alpha; }           \
    const float mc = m_r * csc;                                                \
    float ss[16];                                                              \
    _Pragma("unroll")                                                          \
    for (int i = 0; i < 16; i++) {                                             \
      float p0 = exp2f(s0[i] * csc - mc); s0[i] = p0;                          \
      float p1 = exp2f(s1[i] * csc - mc); s1[i] = p1;                          \
      ss[i] = p0 + p1;                                                         \
    }                                                                          \
    _Pragma("unroll")                                                          \
    for (int st = 8; st >= 1; st >>= 1)                                        \
      _Pragma("unroll")                                                        \
      for (int i = 0; i < st; i++) ss[i] += ss[i + st];                        \
    l_r += ss[0] + __shfl_xor(ss[0], 32);                                      \
    _Pragma("unroll")                                                          \
    for (int kkt = 0; kkt < 4; kkt++) {                                        \
      const int r0 = (kkt & 1) * 8;                                            \
      u32 w0, w1, w2, w3;                                                      \
      if (kkt < 2) {                                                           \
        w0 = cvtpk_bf16(s0[r0],     s0[r0 + 1]);                               \
        w1 = cvtpk_bf16(s0[r0 + 2], s0[r0 + 3]);                               \
        w2 = cvtpk_bf16(s0[r0 + 4], s0[r0 + 5]);                               \
        w3 = cvtpk_bf16(s0[r0 + 6], s0[r0 + 7]);                               \
      } else {                                                                 \
        w0 = cvtpk_bf16(s1[r0],     s1[r0 + 1]);                               \
        w1 = cvtpk_bf16(s1[r0 + 2], s1[r0 + 3]);                               \
        w2 = cvtpk_bf16(s1[r0 + 4], s1[r0 + 5]);                               \
        w3 = cvtpk_bf16(s1[r0 + 6], s1[r0 + 7]);                               \
      }                                                                        \
      asm("v_permlane32_swap_b32 %0, %1" : "+v"(w0), "+v"(w2));                \
      asm("v_permlane32_swap_b32 %0, %1" : "+v"(w1), "+v"(w3));                \
      u32x4 pw = {w0, w1, w2, w3};                                             \
      bf16x8 pf = __builtin_bit_cast(bf16x8, pw);                              \
      __builtin_amdgcn_s_setprio(1);                                           \
      o0 = __builtin_amdgcn_mfma_f32_32x32x16_bf16(vf[kkt],     pf, o0, 0, 0, 0); \
      o1 = __builtin_amdgcn_mfma_f32_32x32x16_bf16(vf[4 + kkt], pf, o1, 0, 0, 0); \
      __builtin_amdgcn_s_setprio(0);                                           \
    }                                                                          \
  }

__global__ __launch_bounds__(256, 2) void attn_fwd(
    const __bf16* __restrict__ QKV, const __bf16* __restrict__ VT,
    __bf16* __restrict__ Z) {
    const int S = 2048, LDQ = 3072;
    // Bijective XCD-chunk swizzle (grid 1024, 1024%8==0): XCD x = d%8 gets
    // logical blocks [x*128,(x+1)*128) -> 8 heads' K/V = 4MB, fits its L2.
    const int d = blockIdx.x;
    const int blk = (d & 7) * 128 + (d >> 3);
    const int qt = blk & 15, bh = blk >> 4, b = bh >> 4, h = bh & 15;
    const int tid = threadIdx.x, wid = tid >> 6, lane = tid & 63;
    const int l31 = lane & 31, hi = lane >> 5;

    __shared__ __bf16 Tl[128][72];   // epilogue transpose only (pad 72)

    const __bf16* Qb = QKV + (size_t)b * S * LDQ + h * 64;
    const __bf16* Kb = Qb + 1024;
    const __bf16* Vb = VT + (size_t)bh * 64 * S;
    const int qrow = qt * 128 + wid * 32;

    bf16x8 qf[4];
#pragma unroll
    for (int kk = 0; kk < 4; kk++)
        qf[kk] = *(const bf16x8*)(Qb + (size_t)(qrow + l31) * LDQ + kk * 16 + hi * 8);

    f32x16 o0 = fzero16(), o1 = fzero16();
    float m_r = -1e30f, l_r = 0.f;
    const float csc = 0.18033688011f;   // log2(e) / sqrt(64)

    bf16x8 kA[8], kB[8];
#pragma unroll
    for (int f = 0; f < 8; f++) {
        const int tc = f >> 2, kk = f & 3;
        kA[f] = *(const bf16x8*)(Kb + (size_t)(tc * 32 + l31) * LDQ + kk * 16 + hi * 8);
    }

    for (int t0 = 0; t0 < S; t0 += 128) {
        ATTN_TILE(t0,      kA, kB, true)
        ATTN_TILE(t0 + 64, kB, kA, (t0 + 128 < S))
    }

    // ---- epilogue: normalize, transpose via LDS, coalesced store ----
    const float inv = 1.0f / l_r;
    const int trow = wid * 32 + l31;
#pragma unroll
    for (int g = 0; g < 4; g++) {
        bf16x4 t4a, t4b;
#pragma unroll
        for (int j = 0; j < 4; j++) {
            t4a[j] = (__bf16)(o0[4 * g + j] * inv);
            t4b[j] = (__bf16)(o1[4 * g + j] * inv);
        }
        *(bf16x4*)&Tl[trow][g * 8 + hi * 4]      = t4a;   // d = 8g+4hi+j
        *(bf16x4*)&Tl[trow][32 + g * 8 + hi * 4] = t4b;   // d = 32+8g+4hi+j
    }
    asm volatile("s_waitcnt lgkmcnt(0)" ::: "memory");
    __builtin_amdgcn_sched_barrier(0);

    const int rr = wid * 32 + (lane >> 1);
    const int ch = (lane & 1) * 32;
#pragma unroll
    for (int i = 0; i < 4; i++) {
        bf16x8 z = *(const bf16x8*)&Tl[rr][ch + i * 8];
        *(bf16x8*)&Z[((size_t)b * S + qt * 128 + rr) * 1024 + h * 64 + ch + i * 8] = z;
    }
}

// ---------------------------------------------------------------------------
// Launcher
// ---------------------------------------------------------------------------
extern "C" void kernel_launch(void* const* d_in, const int* in_sizes, int n_in,
                              void* d_out, int out_size, void* d_ws, size_t ws_size,
                              hipStream_t stream) {
    const float* x  = (const float*)d_in[0];
    const float* Wq = (const float*)d_in[1];
    const float* Wk = (const float*)d_in[2];
    const float* Wv = (const float*)d_in[3];
    const float* bq = (const float*)d_in[4];
    const float* bk = (const float*)d_in[5];
    const float* bv = (const float*)d_in[6];
    const float* Wo = (const float*)d_in[7];
    const float* bo = (const float*)d_in[8];
    float* out = (float*)d_out;

    // workspace carve-up (~109 MB)
    char* p = (char*)d_ws;
    __bf16* xb   = (__bf16*)p; p += 8192L * 1024 * 2;
    __bf16* Wqkv = (__bf16*)p; p += 3072L * 1024 * 2;
    float*  bqkv = (float*)p;  p += 3072L * 4;
    __bf16* QKV  = (__bf16*)p; p += 8192L * 3072 * 2;
    __bf16* VTb  = (__bf16*)p; p += 64L * 64 * 2048 * 2;
    __bf16* Zb   = (__bf16*)p; p += 8192L * 1024 * 2;
    __bf16* Wot  = (__bf16*)p; p += 1024L * 1024 * 2;

    cvt_f32_bf16_4<<<8192, 256, 0, stream>>>(x, xb, 8192L * 1024);
    pack_w_t<<<dim3(32, 2, 16), dim3(32, 8), 0, stream>>>(Wq, Wqkv,                1024, 64);
    pack_w_t<<<dim3(32, 2, 16), dim3(32, 8), 0, stream>>>(Wk, Wqkv + 1024L * 1024, 1024, 64);
    pack_w_t<<<dim3(32, 2, 16), dim3(32, 8), 0, stream>>>(Wv, Wqkv + 2048L * 1024, 1024, 64);
    pack_w_t<<<dim3(32, 32, 1), dim3(32, 8), 0, stream>>>(Wo, Wot, 1024, 1024);
    pack_bias<<<12, 256, 0, stream>>>(bq, bk, bv, bqkv);

    // QKV projection: [8192,1024] x [1024,3072] + bias -> bf16 [8192,3072]
    gemm_bt<false><<<dim3(24, 64), 256, 0, stream>>>(xb, Wqkv, bqkv, QKV,
                                                     8192, 3072, 1024, 3072);
    repack_vt<<<dim3(64, 2, 64), dim3(32, 8), 0, stream>>>(QKV, VTb);
    attn_fwd<<<1024, 256, 0, stream>>>(QKV, VTb, Zb);
    // out projection: [8192,1024] x [1024,1024] + bo -> f32 out
    gemm_bt<true><<<dim3(8, 64), 256, 0, stream>>>(Zb, Wot, bo, out,
                                                   8192, 1024, 1024, 1024);
}

// Round 9
// 240.102 us; speedup vs baseline: 1.5292x; 1.5123x over previous
//
#include <hip/hip_runtime.h>

// ---------------------------------------------------------------------------
// Fused multi-head self-attention, MI355X bf16-MFMA implementation.
// B=4, S=2048, E=1024, H=16, D=64.
// Pipeline: cvt x->bf16 | pack W^T bf16 | GEMM1 (QKV proj, bias) |
//           repack V->V^T | flash-attn (swapped-QK^T, in-reg softmax,
//           LDS-staged K/V double-buffer) | GEMM2 (out proj, bias, f32 out)
// ---------------------------------------------------------------------------

typedef __attribute__((ext_vector_type(4)))  float   f32x4;
typedef __attribute__((ext_vector_type(16))) float   f32x16;
typedef __attribute__((ext_vector_type(8)))  __bf16  bf16x8;
typedef __attribute__((ext_vector_type(4)))  __bf16  bf16x4;
typedef __attribute__((ext_vector_type(4)))  unsigned int u32x4;
typedef unsigned int u32;

#if __has_builtin(__builtin_amdgcn_exp2f)
#define EXP2F(x) __builtin_amdgcn_exp2f(x)
#else
#define EXP2F(x) exp2f(x)
#endif

__device__ __forceinline__ f32x4 fzero4() {
    f32x4 z = {0.f, 0.f, 0.f, 0.f};
    return z;
}
__device__ __forceinline__ f32x16 fzero16() {
    f32x16 z;
#pragma unroll
    for (int i = 0; i < 16; i++) z[i] = 0.f;
    return z;
}

__device__ __forceinline__ u32 cvtpk_bf16(float lo, float hi_) {
    u32 r;
    asm("v_cvt_pk_bf16_f32 %0, %1, %2" : "=v"(r) : "v"(lo), "v"(hi_));
    return r;
}

__device__ __forceinline__ void gload_lds16(const void* g, void* l) {
    __builtin_amdgcn_global_load_lds(
        (const __attribute__((address_space(1))) u32*)g,
        (__attribute__((address_space(3))) u32*)l, 16, 0, 0);
}

// ---------------------------------------------------------------------------
// fp32 -> bf16 elementwise convert (4 elems/thread, vectorized)
// ---------------------------------------------------------------------------
__global__ __launch_bounds__(256) void cvt_f32_bf16_4(
    const float* __restrict__ s, __bf16* __restrict__ d, long n) {
    long i = ((long)blockIdx.x * 256 + threadIdx.x) * 4;
    if (i >= n) return;
    float4 v = *(const float4*)(s + i);
    bf16x4 o = { (__bf16)v.x, (__bf16)v.y, (__bf16)v.z, (__bf16)v.w };
    *(bf16x4*)(d + i) = o;
}

// ---------------------------------------------------------------------------
// Batched transpose-pack: src f32 [z][R][C] -> dst bf16 [z][C][R]
// ---------------------------------------------------------------------------
__global__ __launch_bounds__(256) void pack_w_t(
    const float* __restrict__ src, __bf16* __restrict__ dst, int R, int C) {
    __shared__ float t[32][33];
    const int z = blockIdx.z;
    src += (size_t)z * R * C;
    dst += (size_t)z * R * C;
    const int r0 = blockIdx.x * 32, c0 = blockIdx.y * 32;
    const int x = threadIdx.x, y = threadIdx.y;
#pragma unroll
    for (int i = 0; i < 4; i++)
        t[y + i * 8][x] = src[(size_t)(r0 + y + i * 8) * C + c0 + x];
    __syncthreads();
#pragma unroll
    for (int i = 0; i < 4; i++)
        dst[(size_t)(c0 + y + i * 8) * R + r0 + x] = (__bf16)t[x][y + i * 8];
}

// ---------------------------------------------------------------------------
// bias pack: bqkv[t*1024 + r] = {bq,bk,bv}[r]
// ---------------------------------------------------------------------------
__global__ __launch_bounds__(256) void pack_bias(
    const float* __restrict__ bq, const float* __restrict__ bk,
    const float* __restrict__ bv, float* __restrict__ bqkv) {
    int n = blockIdx.x * 256 + threadIdx.x;
    if (n >= 3072) return;
    int t = n >> 10, r = n & 1023;
    const float* s = (t == 0) ? bq : (t == 1) ? bk : bv;
    bqkv[n] = s[r];
}

// ---------------------------------------------------------------------------
// GEMM, m97 structure: C[M][N](+bias) = A[M][K] * Bt[N][K]^T
// 128x128 tile, BK=32, 256 threads (4 waves 2x2), global_load_lds staging.
// ---------------------------------------------------------------------------
template <bool F32OUT>
__global__ __launch_bounds__(256) void gemm_bt(
    const __bf16* __restrict__ A, const __bf16* __restrict__ Bt,
    const float* __restrict__ bias, void* __restrict__ Cout,
    int M, int N, int K, int ldc) {
    __shared__ __bf16 As[128 * 32];
    __shared__ __bf16 Bs[128 * 32];
    const int tid  = threadIdx.x;
    const int lane = tid & 63, wid = tid >> 6;
    const int wr = wid >> 1, wc = wid & 1;
    const int l15 = lane & 15, l4 = lane >> 4;
    const int bn = blockIdx.x, bm = blockIdx.y;
    const long arow = (long)bm * 128 + (tid >> 2);
    const long brow = (long)bn * 128 + (tid >> 2);
    const int  kcol = (tid & 3) * 8;

    f32x4 acc[4][4];
#pragma unroll
    for (int i = 0; i < 4; i++)
#pragma unroll
        for (int j = 0; j < 4; j++) acc[i][j] = fzero4();

    for (int k0 = 0; k0 < K; k0 += 32) {
        gload_lds16(A + arow * K + k0 + kcol,        (char*)As + wid * 1024);
        gload_lds16(A + (arow + 64) * K + k0 + kcol, (char*)As + 4096 + wid * 1024);
        gload_lds16(Bt + brow * K + k0 + kcol,        (char*)Bs + wid * 1024);
        gload_lds16(Bt + (brow + 64) * K + k0 + kcol, (char*)Bs + 4096 + wid * 1024);
        __syncthreads();
        bf16x8 a[4], b[4];
#pragma unroll
        for (int mi = 0; mi < 4; mi++)
            a[mi] = *(const bf16x8*)&As[(wr * 64 + mi * 16 + l15) * 32 + l4 * 8];
#pragma unroll
        for (int ni = 0; ni < 4; ni++)
            b[ni] = *(const bf16x8*)&Bs[(wc * 64 + ni * 16 + l15) * 32 + l4 * 8];
#pragma unroll
        for (int mi = 0; mi < 4; mi++)
#pragma unroll
            for (int ni = 0; ni < 4; ni++)
                acc[mi][ni] = __builtin_amdgcn_mfma_f32_16x16x32_bf16(
                    a[mi], b[ni], acc[mi][ni], 0, 0, 0);
        __syncthreads();
    }

#pragma unroll
    for (int mi = 0; mi < 4; mi++)
#pragma unroll
        for (int ni = 0; ni < 4; ni++) {
            const int row = bm * 128 + wr * 64 + mi * 16 + l4 * 4;
            const int col = bn * 128 + wc * 64 + ni * 16 + l15;
            const float bv = bias ? bias[col] : 0.f;
#pragma unroll
            for (int r = 0; r < 4; r++) {
                float v = acc[mi][ni][r] + bv;
                if (F32OUT)
                    ((float*)Cout)[(long)(row + r) * ldc + col] = v;
                else
                    ((__bf16*)Cout)[(long)(row + r) * ldc + col] = (__bf16)v;
            }
        }
}

// ---------------------------------------------------------------------------
// V repack: QKV[(b*S+s)*3072 + 2048 + h*64 + d] -> VT[(bh*64 + d)*2048 + s]
// ---------------------------------------------------------------------------
__global__ __launch_bounds__(256) void repack_vt(
    const __bf16* __restrict__ QKV, __bf16* __restrict__ VT) {
    __shared__ __bf16 t[32][33];
    const int s0 = blockIdx.x * 32, d0 = blockIdx.y * 32, bh = blockIdx.z;
    const int b = bh >> 4, h = bh & 15;
    const int x = threadIdx.x, y = threadIdx.y;
    const __bf16* src = QKV + (size_t)(b * 2048) * 3072 + 2048 + h * 64;
#pragma unroll
    for (int i = 0; i < 4; i++)
        t[y + i * 8][x] = src[(size_t)(s0 + y + i * 8) * 3072 + d0 + x];
    __syncthreads();
    __bf16* dst = VT + (size_t)bh * 64 * 2048;
#pragma unroll
    for (int i = 0; i < 4; i++)
        dst[(size_t)(d0 + y + i * 8) * 2048 + s0 + x] = t[x][y + i * 8];
}

// ---------------------------------------------------------------------------
// Flash attention fwd, v9: K AND V staged through LDS (global_load_lds,
// 2-phase double buffer, both-sides XOR swizzle) to kill the 4x-redundant
// per-wave K/V loads and free ~90 VGPRs -> __launch_bounds__(256,4) for
// double occupancy (r8 showed attn insensitive to memory residency; the
// stall is dependency latency at ~2 waves/SIMD -> cure is TLP).
// LDS map (bytes): K0@0, K1@8192, V0@16384, V1@24576; epilogue Tl overlays.
// Swizzle: LDS[r][c] = G[r][c ^ (r&7)] (16B col blocks), read at c ^ (r&7).
// Staged via pre-swizzled global source (rule: gload_lds dest is linear).
// Block = (b, h, 128-row Q tile); 4 waves x 32 q-rows. KV tile = 64.
//   S^T = mfma(A=K, B=Q):   lane q-col = lane&31 -> ONE q row per lane.
//   O^T = mfma(A=V^T, B=P^T): same lane->q mapping, scalar m/l/alpha.
// ---------------------------------------------------------------------------
__global__ __launch_bounds__(256, 4) void attn_fwd(
    const __bf16* __restrict__ QKV, const __bf16* __restrict__ VT,
    __bf16* __restrict__ Z) {
    const int S = 2048, LDQ = 3072;
    // Bijective XCD-chunk swizzle (kept from r8: FETCH 139->25MB, free).
    const int dd = blockIdx.x;
    const int blk = (dd & 7) * 128 + (dd >> 3);
    const int qt = blk & 15, bh = blk >> 4, b = bh >> 4, h = bh & 15;
    const int tid = threadIdx.x, wid = tid >> 6, lane = tid & 63;
    const int l31 = lane & 31, hi = lane >> 5, ln7 = lane & 7;

    __shared__ __bf16 smem[16384];   // 32 KB

    const __bf16* Qb = QKV + (size_t)b * S * LDQ + h * 64;
    const __bf16* Kb = Qb + 1024;
    const __bf16* Vb = VT + (size_t)bh * 64 * S;
    const int qrow = qt * 128 + wid * 32;

    bf16x8 qf[4];
#pragma unroll
    for (int kk = 0; kk < 4; kk++)
        qf[kk] = *(const bf16x8*)(Qb + (size_t)(qrow + l31) * LDQ + kk * 16 + hi * 8);

    // staging geometry: wave wid stages 8-row chunks i0,i1 of each 64x64 tile.
    const int srow = lane >> 3;            // row within chunk (0..7)
    const int scol = ln7 ^ srow;           // pre-swizzled source col-block
    const int i0 = wid * 2, i1 = wid * 2 + 1;
    const int r0s = i0 * 8 + srow, r1s = i1 * 8 + srow;

    f32x16 o0 = fzero16(), o1 = fzero16();
    float m_r = -1e30f, l_r = 0.f;
    const float csc = 0.18033688011f;   // log2(e) / sqrt(64)

    // prologue: stage tile 0 into buffer 0
    gload_lds16(Kb + (size_t)r0s * LDQ + scol * 8, (char*)smem + i0 * 1024);
    gload_lds16(Kb + (size_t)r1s * LDQ + scol * 8, (char*)smem + i1 * 1024);
    gload_lds16(Vb + (size_t)r0s * S + scol * 8,   (char*)smem + 16384 + i0 * 1024);
    gload_lds16(Vb + (size_t)r1s * S + scol * 8,   (char*)smem + 16384 + i1 * 1024);
    asm volatile("s_waitcnt vmcnt(0)" ::: "memory");
    __syncthreads();

    int cur = 0;
    for (int t0 = 0; t0 < S; t0 += 64, cur ^= 1) {
        // ---- stage next tile into the other buffer (overlaps compute) ----
        if (t0 + 64 < S) {
            char* kl = (char*)smem + (cur ^ 1) * 8192;
            char* vl = (char*)smem + 16384 + (cur ^ 1) * 8192;
            gload_lds16(Kb + (size_t)(t0 + 64 + r0s) * LDQ + scol * 8, kl + i0 * 1024);
            gload_lds16(Kb + (size_t)(t0 + 64 + r1s) * LDQ + scol * 8, kl + i1 * 1024);
            gload_lds16(Vb + (size_t)r0s * S + t0 + 64 + scol * 8,     vl + i0 * 1024);
            gload_lds16(Vb + (size_t)r1s * S + t0 + 64 + scol * 8,     vl + i1 * 1024);
        }
        const char* kbase = (const char*)smem + cur * 8192;
        const char* vbase = (const char*)smem + 16384 + cur * 8192;

        // ---- K frags from LDS (swizzled) + QK^T ----
        bf16x8 kf[8];
#pragma unroll
        for (int f = 0; f < 8; f++) {
            const int tc = f >> 2, kk = f & 3;
            const int r = tc * 32 + l31;
            kf[f] = *(const bf16x8*)(kbase + r * 128 + ((kk * 2 + hi) ^ ln7) * 16);
        }
        f32x16 s0 = fzero16(), s1 = fzero16();
        __builtin_amdgcn_s_setprio(1);
#pragma unroll
        for (int kk = 0; kk < 4; kk++) {
            s0 = __builtin_amdgcn_mfma_f32_32x32x16_bf16(kf[kk],     qf[kk], s0, 0, 0, 0);
            s1 = __builtin_amdgcn_mfma_f32_32x32x16_bf16(kf[4 + kk], qf[kk], s1, 0, 0, 0);
        }
        __builtin_amdgcn_s_setprio(0);

        // ---- online softmax (tree max, unconditional rescale) ----
        float mm[16];
#pragma unroll
        for (int i = 0; i < 16; i++) mm[i] = fmaxf(s0[i], s1[i]);
#pragma unroll
        for (int st = 8; st >= 1; st >>= 1)
#pragma unroll
            for (int i = 0; i < st; i++) mm[i] = fmaxf(mm[i], mm[i + st]);
        const float pm = fmaxf(mm[0], __shfl_xor(mm[0], 32));
        const float mnew = fmaxf(m_r, pm);
        const float alpha = EXP2F((m_r - mnew) * csc);
        m_r = mnew;
        l_r *= alpha;
#pragma unroll
        for (int i = 0; i < 16; i++) { o0[i] *= alpha; o1[i] *= alpha; }
        const float mc = m_r * csc;
        float ss[16];
#pragma unroll
        for (int i = 0; i < 16; i++) {
            float p0 = EXP2F(s0[i] * csc - mc); s0[i] = p0;
            float p1 = EXP2F(s1[i] * csc - mc); s1[i] = p1;
            ss[i] = p0 + p1;
        }
#pragma unroll
        for (int st = 8; st >= 1; st >>= 1)
#pragma unroll
            for (int i = 0; i < st; i++) ss[i] += ss[i + st];
        l_r += ss[0] + __shfl_xor(ss[0], 32);

        // ---- P -> bf16 B-frags in-register; PV from LDS V ----
#pragma unroll
        for (int kkt = 0; kkt < 4; kkt++) {
            const int r0 = (kkt & 1) * 8;
            u32 w0, w1, w2, w3;
            if (kkt < 2) {
                w0 = cvtpk_bf16(s0[r0],     s0[r0 + 1]);
                w1 = cvtpk_bf16(s0[r0 + 2], s0[r0 + 3]);
                w2 = cvtpk_bf16(s0[r0 + 4], s0[r0 + 5]);
                w3 = cvtpk_bf16(s0[r0 + 6], s0[r0 + 7]);
            } else {
                w0 = cvtpk_bf16(s1[r0],     s1[r0 + 1]);
                w1 = cvtpk_bf16(s1[r0 + 2], s1[r0 + 3]);
                w2 = cvtpk_bf16(s1[r0 + 4], s1[r0 + 5]);
                w3 = cvtpk_bf16(s1[r0 + 6], s1[r0 + 7]);
            }
            asm("v_permlane32_swap_b32 %0, %1" : "+v"(w0), "+v"(w2));
            asm("v_permlane32_swap_b32 %0, %1" : "+v"(w1), "+v"(w3));
            u32x4 pw = {w0, w1, w2, w3};
            bf16x8 pf = __builtin_bit_cast(bf16x8, pw);
            bf16x8 vf0 = *(const bf16x8*)(vbase + l31 * 128 +
                                          ((kkt * 2 + hi) ^ ln7) * 16);
            bf16x8 vf1 = *(const bf16x8*)(vbase + (32 + l31) * 128 +
                                          ((kkt * 2 + hi) ^ ln7) * 16);
            __builtin_amdgcn_s_setprio(1);
            o0 = __builtin_amdgcn_mfma_f32_32x32x16_bf16(vf0, pf, o0, 0, 0, 0);
            o1 = __builtin_amdgcn_mfma_f32_32x32x16_bf16(vf1, pf, o1, 0, 0, 0);
            __builtin_amdgcn_s_setprio(0);
        }

        // ---- tile boundary: stage done + all reads of cur done ----
        asm volatile("s_waitcnt vmcnt(0)" ::: "memory");
        __syncthreads();
    }

    // ---- epilogue: normalize, transpose via LDS (overlays smem), store ----
    const float inv = 1.0f / l_r;
    __bf16 (*Tl)[72] = (__bf16 (*)[72])smem;
    const int trow = wid * 32 + l31;
#pragma unroll
    for (int g = 0; g < 4; g++) {
        bf16x4 t4a, t4b;
#pragma unroll
        for (int j = 0; j < 4; j++) {
            t4a[j] = (__bf16)(o0[4 * g + j] * inv);
            t4b[j] = (__bf16)(o1[4 * g + j] * inv);
        }
        *(bf16x4*)&Tl[trow][g * 8 + hi * 4]      = t4a;   // d = 8g+4hi+j
        *(bf16x4*)&Tl[trow][32 + g * 8 + hi * 4] = t4b;   // d = 32+8g+4hi+j
    }
    asm volatile("s_waitcnt lgkmcnt(0)" ::: "memory");
    __builtin_amdgcn_sched_barrier(0);

    const int rr = wid * 32 + (lane >> 1);
    const int ch = (lane & 1) * 32;
#pragma unroll
    for (int i = 0; i < 4; i++) {
        bf16x8 z = *(const bf16x8*)&Tl[rr][ch + i * 8];
        *(bf16x8*)&Z[((size_t)b * S + qt * 128 + rr) * 1024 + h * 64 + ch + i * 8] = z;
    }
}

// ---------------------------------------------------------------------------
// Launcher
// ---------------------------------------------------------------------------
extern "C" void kernel_launch(void* const* d_in, const int* in_sizes, int n_in,
                              void* d_out, int out_size, void* d_ws, size_t ws_size,
                              hipStream_t stream) {
    const float* x  = (const float*)d_in[0];
    const float* Wq = (const float*)d_in[1];
    const float* Wk = (const float*)d_in[2];
    const float* Wv = (const float*)d_in[3];
    const float* bq = (const float*)d_in[4];
    const float* bk = (const float*)d_in[5];
    const float* bv = (const float*)d_in[6];
    const float* Wo = (const float*)d_in[7];
    const float* bo = (const float*)d_in[8];
    float* out = (float*)d_out;

    // workspace carve-up (~109 MB)
    char* p = (char*)d_ws;
    __bf16* xb   = (__bf16*)p; p += 8192L * 1024 * 2;
    __bf16* Wqkv = (__bf16*)p; p += 3072L * 1024 * 2;
    float*  bqkv = (float*)p;  p += 3072L * 4;
    __bf16* QKV  = (__bf16*)p; p += 8192L * 3072 * 2;
    __bf16* VTb  = (__bf16*)p; p += 64L * 64 * 2048 * 2;
    __bf16* Zb   = (__bf16*)p; p += 8192L * 1024 * 2;
    __bf16* Wot  = (__bf16*)p; p += 1024L * 1024 * 2;

    cvt_f32_bf16_4<<<8192, 256, 0, stream>>>(x, xb, 8192L * 1024);
    pack_w_t<<<dim3(32, 2, 16), dim3(32, 8), 0, stream>>>(Wq, Wqkv,                1024, 64);
    pack_w_t<<<dim3(32, 2, 16), dim3(32, 8), 0, stream>>>(Wk, Wqkv + 1024L * 1024, 1024, 64);
    pack_w_t<<<dim3(32, 2, 16), dim3(32, 8), 0, stream>>>(Wv, Wqkv + 2048L * 1024, 1024, 64);
    pack_w_t<<<dim3(32, 32, 1), dim3(32, 8), 0, stream>>>(Wo, Wot, 1024, 1024);
    pack_bias<<<12, 256, 0, stream>>>(bq, bk, bv, bqkv);

    // QKV projection: [8192,1024] x [1024,3072] + bias -> bf16 [8192,3072]
    gemm_bt<false><<<dim3(24, 64), 256, 0, stream>>>(xb, Wqkv, bqkv, QKV,
                                                     8192, 3072, 1024, 3072);
    repack_vt<<<dim3(64, 2, 64), dim3(32, 8), 0, stream>>>(QKV, VTb);
    attn_fwd<<<1024, 256, 0, stream>>>(QKV, VTb, Zb);
    // out projection: [8192,1024] x [1024,1024] + bo -> f32 out
    gemm_bt<true><<<dim3(8, 64), 256, 0, stream>>>(Zb, Wot, bo, out,
                                                   8192, 1024, 1024, 1024);
}

// Round 10
// 234.292 us; speedup vs baseline: 1.5671x; 1.0248x over previous
//
#include <hip/hip_runtime.h>

// ---------------------------------------------------------------------------
// Fused multi-head self-attention, MI355X bf16-MFMA implementation.
// B=4, S=2048, E=1024, H=16, D=64.
// Pipeline: cvt x->bf16 | pack W^T bf16 | GEMM1 (QKV proj, bias) |
//           repack V->V^T | flash-attn (swapped-QK^T, in-reg softmax,
//           frag-order LDS K/V double-buffer) | GEMM2 (out proj, bias, f32)
// ---------------------------------------------------------------------------

typedef __attribute__((ext_vector_type(4)))  float   f32x4;
typedef __attribute__((ext_vector_type(16))) float   f32x16;
typedef __attribute__((ext_vector_type(8)))  __bf16  bf16x8;
typedef __attribute__((ext_vector_type(4)))  __bf16  bf16x4;
typedef __attribute__((ext_vector_type(4)))  unsigned int u32x4;
typedef unsigned int u32;

#if __has_builtin(__builtin_amdgcn_exp2f)
#define EXP2F(x) __builtin_amdgcn_exp2f(x)
#else
#define EXP2F(x) exp2f(x)
#endif

__device__ __forceinline__ f32x4 fzero4() {
    f32x4 z = {0.f, 0.f, 0.f, 0.f};
    return z;
}
__device__ __forceinline__ f32x16 fzero16() {
    f32x16 z;
#pragma unroll
    for (int i = 0; i < 16; i++) z[i] = 0.f;
    return z;
}

__device__ __forceinline__ u32 cvtpk_bf16(float lo, float hi_) {
    u32 r;
    asm("v_cvt_pk_bf16_f32 %0, %1, %2" : "=v"(r) : "v"(lo), "v"(hi_));
    return r;
}

__device__ __forceinline__ void gload_lds16(const void* g, void* l) {
    __builtin_amdgcn_global_load_lds(
        (const __attribute__((address_space(1))) u32*)g,
        (__attribute__((address_space(3))) u32*)l, 16, 0, 0);
}

// ---------------------------------------------------------------------------
// fp32 -> bf16 elementwise convert (4 elems/thread, vectorized)
// ---------------------------------------------------------------------------
__global__ __launch_bounds__(256) void cvt_f32_bf16_4(
    const float* __restrict__ s, __bf16* __restrict__ d, long n) {
    long i = ((long)blockIdx.x * 256 + threadIdx.x) * 4;
    if (i >= n) return;
    float4 v = *(const float4*)(s + i);
    bf16x4 o = { (__bf16)v.x, (__bf16)v.y, (__bf16)v.z, (__bf16)v.w };
    *(bf16x4*)(d + i) = o;
}

// ---------------------------------------------------------------------------
// Batched transpose-pack: src f32 [z][R][C] -> dst bf16 [z][C][R]
// ---------------------------------------------------------------------------
__global__ __launch_bounds__(256) void pack_w_t(
    const float* __restrict__ src, __bf16* __restrict__ dst, int R, int C) {
    __shared__ float t[32][33];
    const int z = blockIdx.z;
    src += (size_t)z * R * C;
    dst += (size_t)z * R * C;
    const int r0 = blockIdx.x * 32, c0 = blockIdx.y * 32;
    const int x = threadIdx.x, y = threadIdx.y;
#pragma unroll
    for (int i = 0; i < 4; i++)
        t[y + i * 8][x] = src[(size_t)(r0 + y + i * 8) * C + c0 + x];
    __syncthreads();
#pragma unroll
    for (int i = 0; i < 4; i++)
        dst[(size_t)(c0 + y + i * 8) * R + r0 + x] = (__bf16)t[x][y + i * 8];
}

// ---------------------------------------------------------------------------
// bias pack: bqkv[t*1024 + r] = {bq,bk,bv}[r]
// ---------------------------------------------------------------------------
__global__ __launch_bounds__(256) void pack_bias(
    const float* __restrict__ bq, const float* __restrict__ bk,
    const float* __restrict__ bv, float* __restrict__ bqkv) {
    int n = blockIdx.x * 256 + threadIdx.x;
    if (n >= 3072) return;
    int t = n >> 10, r = n & 1023;
    const float* s = (t == 0) ? bq : (t == 1) ? bk : bv;
    bqkv[n] = s[r];
}

// ---------------------------------------------------------------------------
// GEMM, m97 structure: C[M][N](+bias) = A[M][K] * Bt[N][K]^T
// 128x128 tile, BK=32, 256 threads (4 waves 2x2), global_load_lds staging.
// ---------------------------------------------------------------------------
template <bool F32OUT>
__global__ __launch_bounds__(256) void gemm_bt(
    const __bf16* __restrict__ A, const __bf16* __restrict__ Bt,
    const float* __restrict__ bias, void* __restrict__ Cout,
    int M, int N, int K, int ldc) {
    __shared__ __bf16 As[128 * 32];
    __shared__ __bf16 Bs[128 * 32];
    const int tid  = threadIdx.x;
    const int lane = tid & 63, wid = tid >> 6;
    const int wr = wid >> 1, wc = wid & 1;
    const int l15 = lane & 15, l4 = lane >> 4;
    const int bn = blockIdx.x, bm = blockIdx.y;
    const long arow = (long)bm * 128 + (tid >> 2);
    const long brow = (long)bn * 128 + (tid >> 2);
    const int  kcol = (tid & 3) * 8;

    f32x4 acc[4][4];
#pragma unroll
    for (int i = 0; i < 4; i++)
#pragma unroll
        for (int j = 0; j < 4; j++) acc[i][j] = fzero4();

    for (int k0 = 0; k0 < K; k0 += 32) {
        gload_lds16(A + arow * K + k0 + kcol,        (char*)As + wid * 1024);
        gload_lds16(A + (arow + 64) * K + k0 + kcol, (char*)As + 4096 + wid * 1024);
        gload_lds16(Bt + brow * K + k0 + kcol,        (char*)Bs + wid * 1024);
        gload_lds16(Bt + (brow + 64) * K + k0 + kcol, (char*)Bs + 4096 + wid * 1024);
        __syncthreads();
        bf16x8 a[4], b[4];
#pragma unroll
        for (int mi = 0; mi < 4; mi++)
            a[mi] = *(const bf16x8*)&As[(wr * 64 + mi * 16 + l15) * 32 + l4 * 8];
#pragma unroll
        for (int ni = 0; ni < 4; ni++)
            b[ni] = *(const bf16x8*)&Bs[(wc * 64 + ni * 16 + l15) * 32 + l4 * 8];
#pragma unroll
        for (int mi = 0; mi < 4; mi++)
#pragma unroll
            for (int ni = 0; ni < 4; ni++)
                acc[mi][ni] = __builtin_amdgcn_mfma_f32_16x16x32_bf16(
                    a[mi], b[ni], acc[mi][ni], 0, 0, 0);
        __syncthreads();
    }

#pragma unroll
    for (int mi = 0; mi < 4; mi++)
#pragma unroll
        for (int ni = 0; ni < 4; ni++) {
            const int row = bm * 128 + wr * 64 + mi * 16 + l4 * 4;
            const int col = bn * 128 + wc * 64 + ni * 16 + l15;
            const float bv = bias ? bias[col] : 0.f;
#pragma unroll
            for (int r = 0; r < 4; r++) {
                float v = acc[mi][ni][r] + bv;
                if (F32OUT)
                    ((float*)Cout)[(long)(row + r) * ldc + col] = v;
                else
                    ((__bf16*)Cout)[(long)(row + r) * ldc + col] = (__bf16)v;
            }
        }
}

// ---------------------------------------------------------------------------
// V repack: QKV[(b*S+s)*3072 + 2048 + h*64 + d] -> VT[(bh*64 + d)*2048 + s]
// ---------------------------------------------------------------------------
__global__ __launch_bounds__(256) void repack_vt(
    const __bf16* __restrict__ QKV, __bf16* __restrict__ VT) {
    __shared__ __bf16 t[32][33];
    const int s0 = blockIdx.x * 32, d0 = blockIdx.y * 32, bh = blockIdx.z;
    const int b = bh >> 4, h = bh & 15;
    const int x = threadIdx.x, y = threadIdx.y;
    const __bf16* src = QKV + (size_t)(b * 2048) * 3072 + 2048 + h * 64;
#pragma unroll
    for (int i = 0; i < 4; i++)
        t[y + i * 8][x] = src[(size_t)(s0 + y + i * 8) * 3072 + d0 + x];
    __syncthreads();
    __bf16* dst = VT + (size_t)bh * 64 * 2048;
#pragma unroll
    for (int i = 0; i < 4; i++)
        dst[(size_t)(d0 + y + i * 8) * 2048 + s0 + x] = t[x][y + i * 8];
}

// ---------------------------------------------------------------------------
// Flash attention fwd, v10 = v9 with FRAG-ORDER LDS staging (bank-conflict
// free). global_load_lds takes per-lane SOURCE addresses, so each 1KB LDS
// chunk IS one MFMA fragment: frag f at base + f*1024 + lane*16. A wave's
// ds_read_b128 then covers 64 consecutive 16B spans -> each bank hit 2x
// (free). r9's row-major + XOR swizzle was 4-way conflicted (8.6M conflicts,
// ~12% of time). Staged bytes identical; zero math change.
// LDS map (bytes): Kfrag dbuf [2][8][1024] @0, Vfrag dbuf [2][8][1024] @16384.
//   K frag f (f=tc*4+kk): K[t0 + (f>>2)*32 + l31][(f&3)*16 + hi*8 ..+8]
//   V frag g (g=dc*4+kkt): VT[dc*32 + l31][t0 + (g&3)*16 + hi*8 ..+8]
// Block = (b, h, 128-row Q tile); 4 waves x 32 q-rows. KV tile = 64.
//   S^T = mfma(A=K, B=Q):   lane q-col = lane&31 -> ONE q row per lane.
//   O^T = mfma(A=V^T, B=P^T): same lane->q mapping, scalar m/l/alpha.
// ---------------------------------------------------------------------------
__global__ __launch_bounds__(256, 4) void attn_fwd(
    const __bf16* __restrict__ QKV, const __bf16* __restrict__ VT,
    __bf16* __restrict__ Z) {
    const int S = 2048, LDQ = 3072;
    // Bijective XCD-chunk swizzle (kept from r8: FETCH 139->25MB, free).
    const int dd = blockIdx.x;
    const int blk = (dd & 7) * 128 + (dd >> 3);
    const int qt = blk & 15, bh = blk >> 4, b = bh >> 4, h = bh & 15;
    const int tid = threadIdx.x, wid = tid >> 6, lane = tid & 63;
    const int l31 = lane & 31, hi = lane >> 5;

    __shared__ __bf16 smem[16384];   // 32 KB

    const __bf16* Qb = QKV + (size_t)b * S * LDQ + h * 64;
    const __bf16* Kb = Qb + 1024;
    const __bf16* Vb = VT + (size_t)bh * 64 * S;
    const int qrow = qt * 128 + wid * 32;

    bf16x8 qf[4];
#pragma unroll
    for (int kk = 0; kk < 4; kk++)
        qf[kk] = *(const bf16x8*)(Qb + (size_t)(qrow + l31) * LDQ + kk * 16 + hi * 8);

    // staging geometry: wave wid stages frags f0,f1 of K and V per tile.
    const int f0 = wid * 2, f1 = wid * 2 + 1;
    // K frag f source: row (f>>2)*32 + l31, col (f&3)*16 + hi*8
    const int kr0 = (f0 >> 2) * 32 + l31, kc0 = (f0 & 3) * 16 + hi * 8;
    const int kr1 = (f1 >> 2) * 32 + l31, kc1 = (f1 & 3) * 16 + hi * 8;
    // V frag g source: row (g>>2)*32 + l31 (d), col s = t0 + (g&3)*16 + hi*8
    const int vr0 = kr0, vs0 = kc0;   // same index algebra
    const int vr1 = kr1, vs1 = kc1;
    const int ldst = lane * 16;

    f32x16 o0 = fzero16(), o1 = fzero16();
    float m_r = -1e30f, l_r = 0.f;
    const float csc = 0.18033688011f;   // log2(e) / sqrt(64)

    // prologue: stage tile 0 into buffer 0
    gload_lds16(Kb + (size_t)kr0 * LDQ + kc0, (char*)smem + f0 * 1024 + ldst);
    gload_lds16(Kb + (size_t)kr1 * LDQ + kc1, (char*)smem + f1 * 1024 + ldst);
    gload_lds16(Vb + (size_t)vr0 * S + vs0,   (char*)smem + 16384 + f0 * 1024 + ldst);
    gload_lds16(Vb + (size_t)vr1 * S + vs1,   (char*)smem + 16384 + f1 * 1024 + ldst);
    asm volatile("s_waitcnt vmcnt(0)" ::: "memory");
    __syncthreads();

    int cur = 0;
    for (int t0 = 0; t0 < S; t0 += 64, cur ^= 1) {
        // ---- stage next tile into the other buffer (overlaps compute) ----
        if (t0 + 64 < S) {
            char* kl = (char*)smem + (cur ^ 1) * 8192;
            char* vl = (char*)smem + 16384 + (cur ^ 1) * 8192;
            gload_lds16(Kb + (size_t)(t0 + 64 + kr0) * LDQ + kc0, kl + f0 * 1024 + ldst);
            gload_lds16(Kb + (size_t)(t0 + 64 + kr1) * LDQ + kc1, kl + f1 * 1024 + ldst);
            gload_lds16(Vb + (size_t)vr0 * S + t0 + 64 + vs0,     vl + f0 * 1024 + ldst);
            gload_lds16(Vb + (size_t)vr1 * S + t0 + 64 + vs1,     vl + f1 * 1024 + ldst);
        }
        const char* kbase = (const char*)smem + cur * 8192;
        const char* vbase = (const char*)smem + 16384 + cur * 8192;

        // ---- K frags from LDS (frag-order, conflict-free) + QK^T ----
        bf16x8 kf[8];
#pragma unroll
        for (int f = 0; f < 8; f++)
            kf[f] = *(const bf16x8*)(kbase + f * 1024 + ldst);
        f32x16 s0 = fzero16(), s1 = fzero16();
        __builtin_amdgcn_s_setprio(1);
#pragma unroll
        for (int kk = 0; kk < 4; kk++) {
            s0 = __builtin_amdgcn_mfma_f32_32x32x16_bf16(kf[kk],     qf[kk], s0, 0, 0, 0);
            s1 = __builtin_amdgcn_mfma_f32_32x32x16_bf16(kf[4 + kk], qf[kk], s1, 0, 0, 0);
        }
        __builtin_amdgcn_s_setprio(0);

        // ---- online softmax (tree max, unconditional rescale) ----
        float mm[16];
#pragma unroll
        for (int i = 0; i < 16; i++) mm[i] = fmaxf(s0[i], s1[i]);
#pragma unroll
        for (int st = 8; st >= 1; st >>= 1)
#pragma unroll
            for (int i = 0; i < st; i++) mm[i] = fmaxf(mm[i], mm[i + st]);
        const float pm = fmaxf(mm[0], __shfl_xor(mm[0], 32));
        const float mnew = fmaxf(m_r, pm);
        const float alpha = EXP2F((m_r - mnew) * csc);
        m_r = mnew;
        l_r *= alpha;
#pragma unroll
        for (int i = 0; i < 16; i++) { o0[i] *= alpha; o1[i] *= alpha; }
        const float mc = m_r * csc;
        float ss[16];
#pragma unroll
        for (int i = 0; i < 16; i++) {
            float p0 = EXP2F(s0[i] * csc - mc); s0[i] = p0;
            float p1 = EXP2F(s1[i] * csc - mc); s1[i] = p1;
            ss[i] = p0 + p1;
        }
#pragma unroll
        for (int st = 8; st >= 1; st >>= 1)
#pragma unroll
            for (int i = 0; i < st; i++) ss[i] += ss[i + st];
        l_r += ss[0] + __shfl_xor(ss[0], 32);

        // ---- P -> bf16 B-frags in-register; PV from LDS V (frag-order) ----
#pragma unroll
        for (int kkt = 0; kkt < 4; kkt++) {
            const int r0 = (kkt & 1) * 8;
            u32 w0, w1, w2, w3;
            if (kkt < 2) {
                w0 = cvtpk_bf16(s0[r0],     s0[r0 + 1]);
                w1 = cvtpk_bf16(s0[r0 + 2], s0[r0 + 3]);
                w2 = cvtpk_bf16(s0[r0 + 4], s0[r0 + 5]);
                w3 = cvtpk_bf16(s0[r0 + 6], s0[r0 + 7]);
            } else {
                w0 = cvtpk_bf16(s1[r0],     s1[r0 + 1]);
                w1 = cvtpk_bf16(s1[r0 + 2], s1[r0 + 3]);
                w2 = cvtpk_bf16(s1[r0 + 4], s1[r0 + 5]);
                w3 = cvtpk_bf16(s1[r0 + 6], s1[r0 + 7]);
            }
            asm("v_permlane32_swap_b32 %0, %1" : "+v"(w0), "+v"(w2));
            asm("v_permlane32_swap_b32 %0, %1" : "+v"(w1), "+v"(w3));
            u32x4 pw = {w0, w1, w2, w3};
            bf16x8 pf = __builtin_bit_cast(bf16x8, pw);
            bf16x8 vf0 = *(const bf16x8*)(vbase + kkt * 1024 + ldst);
            bf16x8 vf1 = *(const bf16x8*)(vbase + (4 + kkt) * 1024 + ldst);
            __builtin_amdgcn_s_setprio(1);
            o0 = __builtin_amdgcn_mfma_f32_32x32x16_bf16(vf0, pf, o0, 0, 0, 0);
            o1 = __builtin_amdgcn_mfma_f32_32x32x16_bf16(vf1, pf, o1, 0, 0, 0);
            __builtin_amdgcn_s_setprio(0);
        }

        // ---- tile boundary: stage done + all reads of cur done ----
        asm volatile("s_waitcnt vmcnt(0)" ::: "memory");
        __syncthreads();
    }

    // ---- epilogue: normalize, transpose via LDS (overlays smem), store ----
    const float inv = 1.0f / l_r;
    __bf16 (*Tl)[72] = (__bf16 (*)[72])smem;
    const int trow = wid * 32 + l31;
#pragma unroll
    for (int g = 0; g < 4; g++) {
        bf16x4 t4a, t4b;
#pragma unroll
        for (int j = 0; j < 4; j++) {
            t4a[j] = (__bf16)(o0[4 * g + j] * inv);
            t4b[j] = (__bf16)(o1[4 * g + j] * inv);
        }
        *(bf16x4*)&Tl[trow][g * 8 + hi * 4]      = t4a;   // d = 8g+4hi+j
        *(bf16x4*)&Tl[trow][32 + g * 8 + hi * 4] = t4b;   // d = 32+8g+4hi+j
    }
    asm volatile("s_waitcnt lgkmcnt(0)" ::: "memory");
    __builtin_amdgcn_sched_barrier(0);

    const int rr = wid * 32 + (lane >> 1);
    const int ch = (lane & 1) * 32;
#pragma unroll
    for (int i = 0; i < 4; i++) {
        bf16x8 z = *(const bf16x8*)&Tl[rr][ch + i * 8];
        *(bf16x8*)&Z[((size_t)b * S + qt * 128 + rr) * 1024 + h * 64 + ch + i * 8] = z;
    }
}

// ---------------------------------------------------------------------------
// Launcher
// ---------------------------------------------------------------------------
extern "C" void kernel_launch(void* const* d_in, const int* in_sizes, int n_in,
                              void* d_out, int out_size, void* d_ws, size_t ws_size,
                              hipStream_t stream) {
    const float* x  = (const float*)d_in[0];
    const float* Wq = (const float*)d_in[1];
    const float* Wk = (const float*)d_in[2];
    const float* Wv = (const float*)d_in[3];
    const float* bq = (const float*)d_in[4];
    const float* bk = (const float*)d_in[5];
    const float* bv = (const float*)d_in[6];
    const float* Wo = (const float*)d_in[7];
    const float* bo = (const float*)d_in[8];
    float* out = (float*)d_out;

    // workspace carve-up (~109 MB)
    char* p = (char*)d_ws;
    __bf16* xb   = (__bf16*)p; p += 8192L * 1024 * 2;
    __bf16* Wqkv = (__bf16*)p; p += 3072L * 1024 * 2;
    float*  bqkv = (float*)p;  p += 3072L * 4;
    __bf16* QKV  = (__bf16*)p; p += 8192L * 3072 * 2;
    __bf16* VTb  = (__bf16*)p; p += 64L * 64 * 2048 * 2;
    __bf16* Zb   = (__bf16*)p; p += 8192L * 1024 * 2;
    __bf16* Wot  = (__bf16*)p; p += 1024L * 1024 * 2;

    cvt_f32_bf16_4<<<8192, 256, 0, stream>>>(x, xb, 8192L * 1024);
    pack_w_t<<<dim3(32, 2, 16), dim3(32, 8), 0, stream>>>(Wq, Wqkv,                1024, 64);
    pack_w_t<<<dim3(32, 2, 16), dim3(32, 8), 0, stream>>>(Wk, Wqkv + 1024L * 1024, 1024, 64);
    pack_w_t<<<dim3(32, 2, 16), dim3(32, 8), 0, stream>>>(Wv, Wqkv + 2048L * 1024, 1024, 64);
    pack_w_t<<<dim3(32, 32, 1), dim3(32, 8), 0, stream>>>(Wo, Wot, 1024, 1024);
    pack_bias<<<12, 256, 0, stream>>>(bq, bk, bv, bqkv);

    // QKV projection: [8192,1024] x [1024,3072] + bias -> bf16 [8192,3072]
    gemm_bt<false><<<dim3(24, 64), 256, 0, stream>>>(xb, Wqkv, bqkv, QKV,
                                                     8192, 3072, 1024, 3072);
    repack_vt<<<dim3(64, 2, 64), dim3(32, 8), 0, stream>>>(QKV, VTb);
    attn_fwd<<<1024, 256, 0, stream>>>(QKV, VTb, Zb);
    // out projection: [8192,1024] x [1024,1024] + bo -> f32 out
    gemm_bt<true><<<dim3(8, 64), 256, 0, stream>>>(Zb, Wot, bo, out,
                                                   8192, 1024, 1024, 1024);
}

// Round 12
// 229.355 us; speedup vs baseline: 1.6009x; 1.0215x over previous
//
#include <hip/hip_runtime.h>

// ---------------------------------------------------------------------------
// Fused multi-head self-attention, MI355X bf16-MFMA implementation.
// B=4, S=2048, E=1024, H=16, D=64.
// Pipeline: cvt x->bf16 | pack W^T bf16 | GEMM1 (QKV proj, bias) |
//           repack V->V^T (vectorized) | flash-attn (swapped-QK^T, in-reg
//           softmax, frag-order LDS K/V dbuf, defer-max) | GEMM2
// ---------------------------------------------------------------------------

typedef __attribute__((ext_vector_type(4)))  float   f32x4;
typedef __attribute__((ext_vector_type(16))) float   f32x16;
typedef __attribute__((ext_vector_type(8)))  __bf16  bf16x8;
typedef __attribute__((ext_vector_type(4)))  __bf16  bf16x4;
typedef __attribute__((ext_vector_type(4)))  unsigned int u32x4;
typedef unsigned int u32;

#if __has_builtin(__builtin_amdgcn_exp2f)
#define EXP2F(x) __builtin_amdgcn_exp2f(x)
#else
#define EXP2F(x) exp2f(x)
#endif

__device__ __forceinline__ f32x4 fzero4() {
    f32x4 z = {0.f, 0.f, 0.f, 0.f};
    return z;
}
__device__ __forceinline__ f32x16 fzero16() {
    f32x16 z;
#pragma unroll
    for (int i = 0; i < 16; i++) z[i] = 0.f;
    return z;
}

__device__ __forceinline__ u32 cvtpk_bf16(float lo, float hi_) {
    u32 r;
    asm("v_cvt_pk_bf16_f32 %0, %1, %2" : "=v"(r) : "v"(lo), "v"(hi_));
    return r;
}

__device__ __forceinline__ void gload_lds16(const void* g, void* l) {
    __builtin_amdgcn_global_load_lds(
        (const __attribute__((address_space(1))) u32*)g,
        (__attribute__((address_space(3))) u32*)l, 16, 0, 0);
}

// ---------------------------------------------------------------------------
// fp32 -> bf16 elementwise convert (4 elems/thread, vectorized)
// ---------------------------------------------------------------------------
__global__ __launch_bounds__(256) void cvt_f32_bf16_4(
    const float* __restrict__ s, __bf16* __restrict__ d, long n) {
    long i = ((long)blockIdx.x * 256 + threadIdx.x) * 4;
    if (i >= n) return;
    float4 v = *(const float4*)(s + i);
    bf16x4 o = { (__bf16)v.x, (__bf16)v.y, (__bf16)v.z, (__bf16)v.w };
    *(bf16x4*)(d + i) = o;
}

// ---------------------------------------------------------------------------
// Batched transpose-pack: src f32 [z][R][C] -> dst bf16 [z][C][R]
// ---------------------------------------------------------------------------
__global__ __launch_bounds__(256) void pack_w_t(
    const float* __restrict__ src, __bf16* __restrict__ dst, int R, int C) {
    __shared__ float t[32][33];
    const int z = blockIdx.z;
    src += (size_t)z * R * C;
    dst += (size_t)z * R * C;
    const int r0 = blockIdx.x * 32, c0 = blockIdx.y * 32;
    const int x = threadIdx.x, y = threadIdx.y;
#pragma unroll
    for (int i = 0; i < 4; i++)
        t[y + i * 8][x] = src[(size_t)(r0 + y + i * 8) * C + c0 + x];
    __syncthreads();
#pragma unroll
    for (int i = 0; i < 4; i++)
        dst[(size_t)(c0 + y + i * 8) * R + r0 + x] = (__bf16)t[x][y + i * 8];
}

// ---------------------------------------------------------------------------
// bias pack: bqkv[t*1024 + r] = {bq,bk,bv}[r]
// ---------------------------------------------------------------------------
__global__ __launch_bounds__(256) void pack_bias(
    const float* __restrict__ bq, const float* __restrict__ bk,
    const float* __restrict__ bv, float* __restrict__ bqkv) {
    int n = blockIdx.x * 256 + threadIdx.x;
    if (n >= 3072) return;
    int t = n >> 10, r = n & 1023;
    const float* s = (t == 0) ? bq : (t == 1) ? bk : bv;
    bqkv[n] = s[r];
}

// ---------------------------------------------------------------------------
// GEMM, m97 structure: C[M][N](+bias) = A[M][K] * Bt[N][K]^T
// 128x128 tile, BK=32, 256 threads (4 waves 2x2), global_load_lds staging.
// ---------------------------------------------------------------------------
template <bool F32OUT>
__global__ __launch_bounds__(256) void gemm_bt(
    const __bf16* __restrict__ A, const __bf16* __restrict__ Bt,
    const float* __restrict__ bias, void* __restrict__ Cout,
    int M, int N, int K, int ldc) {
    __shared__ __bf16 As[128 * 32];
    __shared__ __bf16 Bs[128 * 32];
    const int tid  = threadIdx.x;
    const int lane = tid & 63, wid = tid >> 6;
    const int wr = wid >> 1, wc = wid & 1;
    const int l15 = lane & 15, l4 = lane >> 4;
    const int bn = blockIdx.x, bm = blockIdx.y;
    const long arow = (long)bm * 128 + (tid >> 2);
    const long brow = (long)bn * 128 + (tid >> 2);
    const int  kcol = (tid & 3) * 8;

    f32x4 acc[4][4];
#pragma unroll
    for (int i = 0; i < 4; i++)
#pragma unroll
        for (int j = 0; j < 4; j++) acc[i][j] = fzero4();

    for (int k0 = 0; k0 < K; k0 += 32) {
        gload_lds16(A + arow * K + k0 + kcol,        (char*)As + wid * 1024);
        gload_lds16(A + (arow + 64) * K + k0 + kcol, (char*)As + 4096 + wid * 1024);
        gload_lds16(Bt + brow * K + k0 + kcol,        (char*)Bs + wid * 1024);
        gload_lds16(Bt + (brow + 64) * K + k0 + kcol, (char*)Bs + 4096 + wid * 1024);
        __syncthreads();
        bf16x8 a[4], b[4];
#pragma unroll
        for (int mi = 0; mi < 4; mi++)
            a[mi] = *(const bf16x8*)&As[(wr * 64 + mi * 16 + l15) * 32 + l4 * 8];
#pragma unroll
        for (int ni = 0; ni < 4; ni++)
            b[ni] = *(const bf16x8*)&Bs[(wc * 64 + ni * 16 + l15) * 32 + l4 * 8];
#pragma unroll
        for (int mi = 0; mi < 4; mi++)
#pragma unroll
            for (int ni = 0; ni < 4; ni++)
                acc[mi][ni] = __builtin_amdgcn_mfma_f32_16x16x32_bf16(
                    a[mi], b[ni], acc[mi][ni], 0, 0, 0);
        __syncthreads();
    }

#pragma unroll
    for (int mi = 0; mi < 4; mi++)
#pragma unroll
        for (int ni = 0; ni < 4; ni++) {
            const int row = bm * 128 + wr * 64 + mi * 16 + l4 * 4;
            const int col = bn * 128 + wc * 64 + ni * 16 + l15;
            const float bv = bias ? bias[col] : 0.f;
#pragma unroll
            for (int r = 0; r < 4; r++) {
                float v = acc[mi][ni][r] + bv;
                if (F32OUT)
                    ((float*)Cout)[(long)(row + r) * ldc + col] = v;
                else
                    ((__bf16*)Cout)[(long)(row + r) * ldc + col] = (__bf16)v;
            }
        }
}

// ---------------------------------------------------------------------------
// V repack (vectorized, FIXED geometry): QKV[(b*S+s)*3072 + 2048 + h*64 + d]
//   -> VT[(bh*64 + d)*2048 + s].
// Block = 32 s-rows x 64 d-cols = 2048 elems = 256 threads x 8 (exact).
// Load:  r=tdx>>3 (0..31), c=tdx&7 (0..7): 16B contiguous per lane.
// Store: d=tdx>>2 (0..63), sc=tdx&3 (0..3): gather 8 s, 16B store per lane.
// r11's version halved both phases (c=tdx&3 over a 64-wide tile) -> half of
// VT was uninitialized LDS garbage. Pad 68: rows 8 apart -> +16 banks (2-way).
// ---------------------------------------------------------------------------
__global__ __launch_bounds__(256) void repack_vt(
    const __bf16* __restrict__ QKV, __bf16* __restrict__ VT) {
    __shared__ __bf16 t[32][68];
    const int s0 = blockIdx.x * 32, bh = blockIdx.z;
    const int b = bh >> 4, h = bh & 15;
    const int tdx = threadIdx.x;
    const int lr = tdx >> 3, lc = tdx & 7;
    const __bf16* src = QKV + (size_t)(b * 2048 + s0) * 3072 + 2048 + h * 64;
    bf16x8 v = *(const bf16x8*)(src + (size_t)lr * 3072 + lc * 8);
    *(bf16x8*)&t[lr][lc * 8] = v;
    __syncthreads();
    const int d = tdx >> 2, sc = tdx & 3;
    bf16x8 o;
#pragma unroll
    for (int j = 0; j < 8; j++) o[j] = t[sc * 8 + j][d];
    *(bf16x8*)&VT[((size_t)bh * 64 + d) * 2048 + s0 + sc * 8] = o;
}

// ---------------------------------------------------------------------------
// Flash attention fwd, v12 = v11 (unchanged): swapped-QK^T, in-reg softmax,
// frag-order LDS K/V dbuf (bank-conflict free), defer-max (T13), (256,4),
// XCD-chunk swizzle. r11's failure was the repack_vt geometry bug, not
// defer-max (bf16 relative precision is scale-invariant; num/denom scale
// together; l_r <= 2048*e^8 ~ 6e6 << f32 range).
// Block = (b, h, 128-row Q tile); 4 waves x 32 q-rows. KV tile = 64.
//   S^T = mfma(A=K, B=Q):   lane q-col = lane&31 -> ONE q row per lane.
//   O^T = mfma(A=V^T, B=P^T): same lane->q mapping, scalar m/l/alpha.
// ---------------------------------------------------------------------------
__global__ __launch_bounds__(256, 4) void attn_fwd(
    const __bf16* __restrict__ QKV, const __bf16* __restrict__ VT,
    __bf16* __restrict__ Z) {
    const int S = 2048, LDQ = 3072;
    // Bijective XCD-chunk swizzle (kept from r8: FETCH 139->25MB, free).
    const int dd = blockIdx.x;
    const int blk = (dd & 7) * 128 + (dd >> 3);
    const int qt = blk & 15, bh = blk >> 4, b = bh >> 4, h = bh & 15;
    const int tid = threadIdx.x, wid = tid >> 6, lane = tid & 63;
    const int l31 = lane & 31, hi = lane >> 5;

    __shared__ __bf16 smem[16384];   // 32 KB

    const __bf16* Qb = QKV + (size_t)b * S * LDQ + h * 64;
    const __bf16* Kb = Qb + 1024;
    const __bf16* Vb = VT + (size_t)bh * 64 * S;
    const int qrow = qt * 128 + wid * 32;

    bf16x8 qf[4];
#pragma unroll
    for (int kk = 0; kk < 4; kk++)
        qf[kk] = *(const bf16x8*)(Qb + (size_t)(qrow + l31) * LDQ + kk * 16 + hi * 8);

    // staging geometry: wave wid stages frags f0,f1 of K and V per tile.
    const int f0 = wid * 2, f1 = wid * 2 + 1;
    const int kr0 = (f0 >> 2) * 32 + l31, kc0 = (f0 & 3) * 16 + hi * 8;
    const int kr1 = (f1 >> 2) * 32 + l31, kc1 = (f1 & 3) * 16 + hi * 8;
    const int vr0 = kr0, vs0 = kc0;
    const int vr1 = kr1, vs1 = kc1;
    const int ldst = lane * 16;

    f32x16 o0 = fzero16(), o1 = fzero16();
    float m_r = -1e30f, l_r = 0.f;
    const float csc = 0.18033688011f;   // log2(e) / sqrt(64)

    // prologue: stage tile 0 into buffer 0
    gload_lds16(Kb + (size_t)kr0 * LDQ + kc0, (char*)smem + f0 * 1024 + ldst);
    gload_lds16(Kb + (size_t)kr1 * LDQ + kc1, (char*)smem + f1 * 1024 + ldst);
    gload_lds16(Vb + (size_t)vr0 * S + vs0,   (char*)smem + 16384 + f0 * 1024 + ldst);
    gload_lds16(Vb + (size_t)vr1 * S + vs1,   (char*)smem + 16384 + f1 * 1024 + ldst);
    asm volatile("s_waitcnt vmcnt(0)" ::: "memory");
    __syncthreads();

    int cur = 0;
    for (int t0 = 0; t0 < S; t0 += 64, cur ^= 1) {
        // ---- stage next tile into the other buffer (overlaps compute) ----
        if (t0 + 64 < S) {
            char* kl = (char*)smem + (cur ^ 1) * 8192;
            char* vl = (char*)smem + 16384 + (cur ^ 1) * 8192;
            gload_lds16(Kb + (size_t)(t0 + 64 + kr0) * LDQ + kc0, kl + f0 * 1024 + ldst);
            gload_lds16(Kb + (size_t)(t0 + 64 + kr1) * LDQ + kc1, kl + f1 * 1024 + ldst);
            gload_lds16(Vb + (size_t)vr0 * S + t0 + 64 + vs0,     vl + f0 * 1024 + ldst);
            gload_lds16(Vb + (size_t)vr1 * S + t0 + 64 + vs1,     vl + f1 * 1024 + ldst);
        }
        const char* kbase = (const char*)smem + cur * 8192;
        const char* vbase = (const char*)smem + 16384 + cur * 8192;

        // ---- K frags from LDS (frag-order, conflict-free) + QK^T ----
        bf16x8 kf[8];
#pragma unroll
        for (int f = 0; f < 8; f++)
            kf[f] = *(const bf16x8*)(kbase + f * 1024 + ldst);
        f32x16 s0 = fzero16(), s1 = fzero16();
        __builtin_amdgcn_s_setprio(1);
#pragma unroll
        for (int kk = 0; kk < 4; kk++) {
            s0 = __builtin_amdgcn_mfma_f32_32x32x16_bf16(kf[kk],     qf[kk], s0, 0, 0, 0);
            s1 = __builtin_amdgcn_mfma_f32_32x32x16_bf16(kf[4 + kk], qf[kk], s1, 0, 0, 0);
        }
        __builtin_amdgcn_s_setprio(0);

        // ---- online softmax: tree max + defer-max rescale ----
        float mm[16];
#pragma unroll
        for (int i = 0; i < 16; i++) mm[i] = fmaxf(s0[i], s1[i]);
#pragma unroll
        for (int st = 8; st >= 1; st >>= 1)
#pragma unroll
            for (int i = 0; i < st; i++) mm[i] = fmaxf(mm[i], mm[i + st]);
        const float pm = fmaxf(mm[0], __shfl_xor(mm[0], 32));
        if (!__all(pm - m_r <= 64.f)) {          // 64 raw units = e^8 bound
            const float mnew = fmaxf(m_r, pm);
            const float alpha = EXP2F((m_r - mnew) * csc);
            m_r = mnew;
            l_r *= alpha;
#pragma unroll
            for (int i = 0; i < 16; i++) { o0[i] *= alpha; o1[i] *= alpha; }
        }
        const float mc = m_r * csc;
        float ss[16];
#pragma unroll
        for (int i = 0; i < 16; i++) {
            float p0 = EXP2F(s0[i] * csc - mc); s0[i] = p0;
            float p1 = EXP2F(s1[i] * csc - mc); s1[i] = p1;
            ss[i] = p0 + p1;
        }
#pragma unroll
        for (int st = 8; st >= 1; st >>= 1)
#pragma unroll
            for (int i = 0; i < st; i++) ss[i] += ss[i + st];
        l_r += ss[0] + __shfl_xor(ss[0], 32);

        // ---- P -> bf16 B-frags in-register; PV from LDS V (frag-order) ----
        __builtin_amdgcn_s_setprio(1);
#pragma unroll
        for (int kkt = 0; kkt < 4; kkt++) {
            const int r0 = (kkt & 1) * 8;
            u32 w0, w1, w2, w3;
            if (kkt < 2) {
                w0 = cvtpk_bf16(s0[r0],     s0[r0 + 1]);
                w1 = cvtpk_bf16(s0[r0 + 2], s0[r0 + 3]);
                w2 = cvtpk_bf16(s0[r0 + 4], s0[r0 + 5]);
                w3 = cvtpk_bf16(s0[r0 + 6], s0[r0 + 7]);
            } else {
                w0 = cvtpk_bf16(s1[r0],     s1[r0 + 1]);
                w1 = cvtpk_bf16(s1[r0 + 2], s1[r0 + 3]);
                w2 = cvtpk_bf16(s1[r0 + 4], s1[r0 + 5]);
                w3 = cvtpk_bf16(s1[r0 + 6], s1[r0 + 7]);
            }
            asm("v_permlane32_swap_b32 %0, %1" : "+v"(w0), "+v"(w2));
            asm("v_permlane32_swap_b32 %0, %1" : "+v"(w1), "+v"(w3));
            u32x4 pw = {w0, w1, w2, w3};
            bf16x8 pf = __builtin_bit_cast(bf16x8, pw);
            bf16x8 vf0 = *(const bf16x8*)(vbase + kkt * 1024 + ldst);
            bf16x8 vf1 = *(const bf16x8*)(vbase + (4 + kkt) * 1024 + ldst);
            o0 = __builtin_amdgcn_mfma_f32_32x32x16_bf16(vf0, pf, o0, 0, 0, 0);
            o1 = __builtin_amdgcn_mfma_f32_32x32x16_bf16(vf1, pf, o1, 0, 0, 0);
        }
        __builtin_amdgcn_s_setprio(0);

        // ---- tile boundary: stage done + all reads of cur done ----
        asm volatile("s_waitcnt vmcnt(0)" ::: "memory");
        __syncthreads();
    }

    // ---- epilogue: normalize, transpose via LDS (overlays smem), store ----
    const float inv = 1.0f / l_r;
    __bf16 (*Tl)[72] = (__bf16 (*)[72])smem;
    const int trow = wid * 32 + l31;
#pragma unroll
    for (int g = 0; g < 4; g++) {
        bf16x4 t4a, t4b;
#pragma unroll
        for (int j = 0; j < 4; j++) {
            t4a[j] = (__bf16)(o0[4 * g + j] * inv);
            t4b[j] = (__bf16)(o1[4 * g + j] * inv);
        }
        *(bf16x4*)&Tl[trow][g * 8 + hi * 4]      = t4a;   // d = 8g+4hi+j
        *(bf16x4*)&Tl[trow][32 + g * 8 + hi * 4] = t4b;   // d = 32+8g+4hi+j
    }
    asm volatile("s_waitcnt lgkmcnt(0)" ::: "memory");
    __builtin_amdgcn_sched_barrier(0);

    const int rr = wid * 32 + (lane >> 1);
    const int ch = (lane & 1) * 32;
#pragma unroll
    for (int i = 0; i < 4; i++) {
        bf16x8 z = *(const bf16x8*)&Tl[rr][ch + i * 8];
        *(bf16x8*)&Z[((size_t)b * S + qt * 128 + rr) * 1024 + h * 64 + ch + i * 8] = z;
    }
}

// ---------------------------------------------------------------------------
// Launcher
// ---------------------------------------------------------------------------
extern "C" void kernel_launch(void* const* d_in, const int* in_sizes, int n_in,
                              void* d_out, int out_size, void* d_ws, size_t ws_size,
                              hipStream_t stream) {
    const float* x  = (const float*)d_in[0];
    const float* Wq = (const float*)d_in[1];
    const float* Wk = (const float*)d_in[2];
    const float* Wv = (const float*)d_in[3];
    const float* bq = (const float*)d_in[4];
    const float* bk = (const float*)d_in[5];
    const float* bv = (const float*)d_in[6];
    const float* Wo = (const float*)d_in[7];
    const float* bo = (const float*)d_in[8];
    float* out = (float*)d_out;

    // workspace carve-up (~109 MB)
    char* p = (char*)d_ws;
    __bf16* xb   = (__bf16*)p; p += 8192L * 1024 * 2;
    __bf16* Wqkv = (__bf16*)p; p += 3072L * 1024 * 2;
    float*  bqkv = (float*)p;  p += 3072L * 4;
    __bf16* QKV  = (__bf16*)p; p += 8192L * 3072 * 2;
    __bf16* VTb  = (__bf16*)p; p += 64L * 64 * 2048 * 2;
    __bf16* Zb   = (__bf16*)p; p += 8192L * 1024 * 2;
    __bf16* Wot  = (__bf16*)p; p += 1024L * 1024 * 2;

    cvt_f32_bf16_4<<<8192, 256, 0, stream>>>(x, xb, 8192L * 1024);
    pack_w_t<<<dim3(32, 2, 16), dim3(32, 8), 0, stream>>>(Wq, Wqkv,                1024, 64);
    pack_w_t<<<dim3(32, 2, 16), dim3(32, 8), 0, stream>>>(Wk, Wqkv + 1024L * 1024, 1024, 64);
    pack_w_t<<<dim3(32, 2, 16), dim3(32, 8), 0, stream>>>(Wv, Wqkv + 2048L * 1024, 1024, 64);
    pack_w_t<<<dim3(32, 32, 1), dim3(32, 8), 0, stream>>>(Wo, Wot, 1024, 1024);
    pack_bias<<<12, 256, 0, stream>>>(bq, bk, bv, bqkv);

    // QKV projection: [8192,1024] x [1024,3072] + bias -> bf16 [8192,3072]
    gemm_bt<false><<<dim3(24, 64), 256, 0, stream>>>(xb, Wqkv, bqkv, QKV,
                                                     8192, 3072, 1024, 3072);
    repack_vt<<<dim3(64, 1, 64), 256, 0, stream>>>(QKV, VTb);
    attn_fwd<<<1024, 256, 0, stream>>>(QKV, VTb, Zb);
    // out projection: [8192,1024] x [1024,1024] + bo -> f32 out
    gemm_bt<true><<<dim3(8, 64), 256, 0, stream>>>(Zb, Wot, bo, out,
                                                   8192, 1024, 1024, 1024);
}